// Round 5
// baseline (261.593 us; speedup 1.0000x reference)
//
#include <hip/hip_runtime.h>
#include <hip/hip_bf16.h>
#include <cstddef>

#define N_E 400000
#define N_V 50000
#define NEG_SLOPE 0.01f
#define BN_EPS 1e-5f
#define GRID2 512

typedef __attribute__((ext_vector_type(8))) short bf16x8;
typedef __attribute__((ext_vector_type(4))) float f32x4;

// ws layout (bytes)
#define PART_OFF   0            // 64 replicas * 256 f32 = 65536 B
#define SCALE_OFF  65536        // 256 f32 (scale[128], shift[128])
#define WT_OFF     66560        // bf16 weights, packed in MFMA A-frag chunks
// wt shorts: W1a 8192 @0 | W1b 16384 @8192 | W2 16384 @24576 | W3 16384 @40960
#define META_END   181248
#define Y_BYTES    12800000ULL  // 50000*128*2
#define H_BYTES    102400000ULL // 400000*128*2
#define OUT_BYTES  204800000ULL

__device__ __forceinline__ unsigned short f2bf(float f) {
  unsigned u = __builtin_bit_cast(unsigned, f);
  u += 0x7fffu + ((u >> 16) & 1u);            // RNE
  return (unsigned short)(u >> 16);
}
__device__ __forceinline__ float bf2f(unsigned short s) {
  return __builtin_bit_cast(float, (unsigned)s << 16);
}
__device__ __forceinline__ float lrelu(float x) {
  return x >= 0.f ? x : NEG_SLOPE * x;
}
// pack 2 f32 -> 2 bf16 (RNE), lo in low 16 bits
__device__ __forceinline__ unsigned pk2(float lo, float hi) {
  return (unsigned)f2bf(lo) | ((unsigned)f2bf(hi) << 16);
}
// elementwise add of 2 packed bf16 pairs
__device__ __forceinline__ int addbf(int a, int b) {
  unsigned ua = (unsigned)a, ub = (unsigned)b;
  float l = __builtin_bit_cast(float, ua << 16) + __builtin_bit_cast(float, ub << 16);
  float h = __builtin_bit_cast(float, ua & 0xffff0000u) +
            __builtin_bit_cast(float, ub & 0xffff0000u);
  return (int)pk2(l, h);
}

// MFMA over 4 edge-tiles, 1 feature-tile: D[feat][edge]
template<int KS>
__device__ __forceinline__ void runL(const short* sA, int stride, const bf16x8* fr,
                                     f32x4* acc, int lane) {
  const int col = lane & 15;
  const int kb = (lane >> 4) * 8;
  #pragma unroll
  for (int et = 0; et < 4; ++et) {
    const short* bp = sA + (et * 16 + col) * stride + kb;
    #pragma unroll
    for (int s = 0; s < KS; ++s) {
      bf16x8 b = *(const bf16x8*)(bp + s * 32);
      acc[et] = __builtin_amdgcn_mfma_f32_16x16x32_bf16(fr[s], b, acc[et], 0, 0, 0);
    }
  }
}

// epilogue: bias (+y for MODE1) + lrelu (+stats for MODE2) -> bf16 int2 into LDS
template<int MODE>
__device__ __forceinline__ void epiW(f32x4* acc, float4 bb, const short* sYb,
                                     short* dst, int f, int col,
                                     float* sE, float* sQ) {
  #pragma unroll
  for (int et = 0; et < 4; ++et) {
    const int edge = et * 16 + col;
    f32x4 a = acc[et];
    float v0 = a[0] + bb.x, v1 = a[1] + bb.y, v2 = a[2] + bb.z, v3 = a[3] + bb.w;
    if (MODE == 1) {
      short4 q = *(const short4*)(sYb + edge * 136 + f);
      v0 += bf2f((unsigned short)q.x); v1 += bf2f((unsigned short)q.y);
      v2 += bf2f((unsigned short)q.z); v3 += bf2f((unsigned short)q.w);
    }
    v0 = lrelu(v0); v1 = lrelu(v1); v2 = lrelu(v2); v3 = lrelu(v3);
    if (MODE == 2) {
      sE[0] += v0; sQ[0] += v0 * v0; sE[1] += v1; sQ[1] += v1 * v1;
      sE[2] += v2; sQ[2] += v2 * v2; sE[3] += v3; sQ[3] += v3 * v3;
    }
    *(int2*)(dst + edge * 136 + f) = make_int2((int)pk2(v0, v1), (int)pk2(v2, v3));
    acc[et] = (f32x4){0.f, 0.f, 0.f, 0.f};
  }
}

// ---- persistent edge-MLP kernel: 512 thr, 8 waves, 1 feature-tile/wave ----
template<bool USEWS>
__global__ __launch_bounds__(512, 4) void gnn2(
    const float* __restrict__ edgef, const int* __restrict__ srcI,
    const int* __restrict__ dstI, const short* __restrict__ ybuf,
    const float* __restrict__ b1, const float* __restrict__ b2,
    const float* __restrict__ b3, const short* __restrict__ wt,
    float* __restrict__ partials, short* __restrict__ hout,
    float* __restrict__ fout) {
  __shared__ short sX[64 * 72];    // ef tile bf16 (K=64), pad stride 72
  __shared__ short sY[64 * 136];   // ysum tile bf16
  __shared__ short sHa[64 * 136];  // h1 / h3
  __shared__ short sHb[64 * 136];  // h2

  const int tid = threadIdx.x;
  const int lane = tid & 63;
  const int w = tid >> 6;
  const int bid = blockIdx.x;
  const int r8 = tid >> 3, c8 = tid & 7;
  const int col = lane & 15;
  const int f = w * 16 + ((lane >> 4) << 2);

  bf16x8 fr1[2], fr2[4], fr3[4];
  #pragma unroll
  for (int s = 0; s < 2; ++s)
    fr1[s] = *(const bf16x8*)(wt + (((w * 2 + s) << 9) + lane * 8));
  #pragma unroll
  for (int s = 0; s < 4; ++s)
    fr2[s] = *(const bf16x8*)(wt + 24576 + (((w * 4 + s) << 9) + lane * 8));
  #pragma unroll
  for (int s = 0; s < 4; ++s)
    fr3[s] = *(const bf16x8*)(wt + 40960 + (((w * 4 + s) << 9) + lane * 8));

  const float4 bb1 = *(const float4*)(b1 + f);
  const float4 bb2 = *(const float4*)(b2 + f);
  const float4 bb3 = *(const float4*)(b3 + f);

  f32x4 acc[4];
  #pragma unroll
  for (int i = 0; i < 4; ++i) acc[i] = (f32x4){0.f, 0.f, 0.f, 0.f};
  float sE[4] = {0.f, 0.f, 0.f, 0.f}, sQ[4] = {0.f, 0.f, 0.f, 0.f};

  // prologue: stage tile `bid`
  {
    int e = bid * 64 + r8;
    int si = srcI[e], di = dstI[e];
    const float4* efp = (const float4*)(edgef + (size_t)e * 64) + c8 * 2;
    float4 ea = efp[0], eb = efp[1];
    const int4* yps = (const int4*)(ybuf + (size_t)si * 128) + c8 * 2;
    const int4* ypd = (const int4*)(ybuf + (size_t)di * 128) + c8 * 2;
    int4 a0 = yps[0], a1 = yps[1], d0 = ypd[0], d1 = ypd[1];
    int4 ex;
    ex.x = (int)pk2(ea.x, ea.y); ex.y = (int)pk2(ea.z, ea.w);
    ex.z = (int)pk2(eb.x, eb.y); ex.w = (int)pk2(eb.z, eb.w);
    *(int4*)(sX + r8 * 72 + c8 * 8) = ex;
    int4 y0, y1;
    y0.x = addbf(a0.x, d0.x); y0.y = addbf(a0.y, d0.y);
    y0.z = addbf(a0.z, d0.z); y0.w = addbf(a0.w, d0.w);
    y1.x = addbf(a1.x, d1.x); y1.y = addbf(a1.y, d1.y);
    y1.z = addbf(a1.z, d1.z); y1.w = addbf(a1.w, d1.w);
    *(int4*)(sY + r8 * 136 + c8 * 16) = y0;
    *(int4*)(sY + r8 * 136 + c8 * 16 + 8) = y1;
  }
  __syncthreads();

  for (int t = bid; t < N_E / 64; t += GRID2) {
    const int tn = t + GRID2;
    const bool pf = tn < N_E / 64;
    int si = 0, di = 0;
    float4 ea, eb;
    // ---- L1 (K=64) + issue next-tile idx/ef loads ----
    runL<2>(sX, 72, fr1, acc, lane);
    if (pf) {
      int e = tn * 64 + r8;
      si = srcI[e]; di = dstI[e];
      const float4* efp = (const float4*)(edgef + (size_t)e * 64) + c8 * 2;
      ea = efp[0]; eb = efp[1];
    }
    epiW<1>(acc, bb1, sY, sHa, f, col, sE, sQ);
    __syncthreads();
    // ---- L2 + issue next-tile y gathers ----
    runL<4>(sHa, 136, fr2, acc, lane);
    int4 a0, a1, d0, d1;
    if (pf) {
      const int4* yps = (const int4*)(ybuf + (size_t)si * 128) + c8 * 2;
      const int4* ypd = (const int4*)(ybuf + (size_t)di * 128) + c8 * 2;
      a0 = yps[0]; a1 = yps[1]; d0 = ypd[0]; d1 = ypd[1];
    }
    epiW<0>(acc, bb2, sY, sHb, f, col, sE, sQ);
    __syncthreads();
    // ---- L3 + stats + LDS-write next tile ----
    runL<4>(sHb, 136, fr3, acc, lane);
    epiW<2>(acc, bb3, sY, sHa, f, col, sE, sQ);
    if (pf) {
      int4 ex;
      ex.x = (int)pk2(ea.x, ea.y); ex.y = (int)pk2(ea.z, ea.w);
      ex.z = (int)pk2(eb.x, eb.y); ex.w = (int)pk2(eb.z, eb.w);
      *(int4*)(sX + r8 * 72 + c8 * 8) = ex;
      int4 y0, y1;
      y0.x = addbf(a0.x, d0.x); y0.y = addbf(a0.y, d0.y);
      y0.z = addbf(a0.z, d0.z); y0.w = addbf(a0.w, d0.w);
      y1.x = addbf(a1.x, d1.x); y1.y = addbf(a1.y, d1.y);
      y1.z = addbf(a1.z, d1.z); y1.w = addbf(a1.w, d1.w);
      *(int4*)(sY + r8 * 136 + c8 * 16) = y0;
      *(int4*)(sY + r8 * 136 + c8 * 16 + 8) = y1;
    }
    __syncthreads();
    // ---- out: h3 tile -> global (coalesced) ----
    if (USEWS) {
      int4* dst = (int4*)(hout + (size_t)t * 8192);
      #pragma unroll
      for (int j = 0; j < 2; ++j)
        dst[r8 * 16 + c8 * 2 + j] = *(const int4*)(sHa + r8 * 136 + c8 * 16 + j * 8);
    } else {
      float4* dst = (float4*)(fout + (size_t)t * 8192);
      #pragma unroll
      for (int j = 0; j < 2; ++j) {
        int4 tv = *(const int4*)(sHa + r8 * 136 + c8 * 16 + j * 8);
        float4 o0, o1;
        o0.x = bf2f((unsigned short)((unsigned)tv.x & 0xffffu));
        o0.y = bf2f((unsigned short)((unsigned)tv.x >> 16));
        o0.z = bf2f((unsigned short)((unsigned)tv.y & 0xffffu));
        o0.w = bf2f((unsigned short)((unsigned)tv.y >> 16));
        o1.x = bf2f((unsigned short)((unsigned)tv.z & 0xffffu));
        o1.y = bf2f((unsigned short)((unsigned)tv.z >> 16));
        o1.z = bf2f((unsigned short)((unsigned)tv.w & 0xffffu));
        o1.w = bf2f((unsigned short)((unsigned)tv.w >> 16));
        dst[r8 * 32 + c8 * 4 + j * 2] = o0;
        dst[r8 * 32 + c8 * 4 + j * 2 + 1] = o1;
      }
    }
    __syncthreads();
  }

  // stats flush: butterfly over edge lanes then one atomic set per block
  #pragma unroll
  for (int m = 1; m <= 8; m <<= 1) {
    #pragma unroll
    for (int i = 0; i < 4; ++i) {
      sE[i] += __shfl_xor(sE[i], m, 64);
      sQ[i] += __shfl_xor(sQ[i], m, 64);
    }
  }
  if ((lane & 15) == 0) {
    float* pp = partials + (bid & 63) * 256;
    #pragma unroll
    for (int i = 0; i < 4; ++i) {
      atomicAdd(&pp[f + i], sE[i]);
      atomicAdd(&pp[128 + f + i], sQ[i]);
    }
  }
}

// ---- per-node precompute: y = nf * W1b  (bf16 out) ----
__global__ __launch_bounds__(256) void nodeK(const float* __restrict__ nodef,
                                             const short* __restrict__ wt,
                                             short* __restrict__ y) {
  __shared__ short sN[64 * 136];
  const int tid = threadIdx.x;
  const int lane = tid & 63;
  const int w = tid >> 6;
  const int n0 = blockIdx.x * 64;
  const int r = tid >> 2, p4 = tid & 3;
  {
    int v = n0 + r;
    int vc = v < N_V ? v : N_V - 1;
    const float4* np = (const float4*)(nodef + (size_t)vc * 128) + p4 * 8;
    #pragma unroll
    for (int j = 0; j < 8; ++j) {
      float4 a = np[j];
      *(int2*)(sN + r * 136 + p4 * 32 + j * 4) =
          make_int2((int)pk2(a.x, a.y), (int)pk2(a.z, a.w));
    }
  }
  __syncthreads();
  const short* wb = wt + 8192;
  bf16x8 fr[8];
  #pragma unroll
  for (int nt = 0; nt < 2; ++nt)
    #pragma unroll
    for (int s = 0; s < 4; ++s)
      fr[nt * 4 + s] = *(const bf16x8*)(wb + ((((w * 2 + nt) * 4 + s) << 9) + lane * 8));
  f32x4 acc[8];
  #pragma unroll
  for (int i = 0; i < 8; ++i) acc[i] = (f32x4){0.f, 0.f, 0.f, 0.f};
  const int col = lane & 15;
  const int kb = (lane >> 4) * 8;
  #pragma unroll
  for (int et = 0; et < 4; ++et) {
    const short* bp = sN + (et * 16 + col) * 136 + kb;
    #pragma unroll
    for (int s = 0; s < 4; ++s) {
      bf16x8 b = *(const bf16x8*)(bp + s * 32);
      acc[0 + et] = __builtin_amdgcn_mfma_f32_16x16x32_bf16(fr[s], b, acc[0 + et], 0, 0, 0);
      acc[4 + et] = __builtin_amdgcn_mfma_f32_16x16x32_bf16(fr[4 + s], b, acc[4 + et], 0, 0, 0);
    }
  }
  __syncthreads();   // sN input reads done
  {
    const int fb = (lane >> 4) * 4;
    #pragma unroll
    for (int nt = 0; nt < 2; ++nt) {
      const int f0 = w * 32 + nt * 16 + fb;
      #pragma unroll
      for (int et = 0; et < 4; ++et) {
        f32x4 a = acc[nt * 4 + et];
        *(int2*)(sN + (et * 16 + col) * 136 + f0) =
            make_int2((int)pk2(a[0], a[1]), (int)pk2(a[2], a[3]));
      }
    }
  }
  __syncthreads();
  if (n0 + r < N_V) {
    #pragma unroll
    for (int j = 0; j < 4; ++j) {   // FIX: 4 int4 = 32 shorts per thread (was 2 -> half row missing)
      int4 tv = *(const int4*)(sN + r * 136 + p4 * 32 + j * 8);
      *(int4*)(y + (size_t)(n0 + r) * 128 + p4 * 32 + j * 8) = tv;
    }
  }
}

// ---- weight pack + partials zero ----
__global__ __launch_bounds__(256) void prepK(const float* __restrict__ W1,
                                             const float* __restrict__ W2,
                                             const float* __restrict__ W3,
                                             short* __restrict__ wt,
                                             float* __restrict__ partials) {
  int b = blockIdx.x, t = threadIdx.x;
  if (b < 64) { partials[b * 256 + t] = 0.f; return; }
  int g = (b - 64) * 256 + t;
  for (int fi = g; fi < 57344; fi += 32 * 256) {
    float val;
    if (fi < 8192) {                       // W1a: 8 tiles x 2 ksteps (K=64)
      int c = fi >> 9, r = fi & 511;
      int l = r >> 3, j = r & 7;
      int tt = c >> 1, s = c & 1;
      int n = tt * 16 + (l & 15);
      int k = s * 32 + (l >> 4) * 8 + j;
      val = W1[k * 128 + n];
    } else if (fi < 24576) {               // W1b: 8 tiles x 4 ksteps (rows 64..191)
      int f2 = fi - 8192;
      int c = f2 >> 9, r = f2 & 511;
      int l = r >> 3, j = r & 7;
      int tt = c >> 2, s = c & 3;
      int n = tt * 16 + (l & 15);
      int k = s * 32 + (l >> 4) * 8 + j;
      val = W1[(64 + k) * 128 + n];
    } else if (fi < 40960) {               // W2
      int f2 = fi - 24576;
      int c = f2 >> 9, r = f2 & 511;
      int l = r >> 3, j = r & 7;
      int tt = c >> 2, s = c & 3;
      int n = tt * 16 + (l & 15);
      int k = s * 32 + (l >> 4) * 8 + j;
      val = W2[k * 128 + n];
    } else {                               // W3
      int f3 = fi - 40960;
      int c = f3 >> 9, r = f3 & 511;
      int l = r >> 3, j = r & 7;
      int tt = c >> 2, s = c & 3;
      int n = tt * 16 + (l & 15);
      int k = s * 32 + (l >> 4) * 8 + j;
      val = W3[k * 128 + n];
    }
    wt[fi] = (short)f2bf(val);
  }
}

__global__ __launch_bounds__(256) void statsK(const float* __restrict__ partials,
                                              const float* __restrict__ gamma,
                                              const float* __restrict__ beta,
                                              float* __restrict__ scsh) {
  __shared__ float tmp[256];
  int t = threadIdx.x;
  float a = 0.f;
  #pragma unroll 8
  for (int r = 0; r < 64; ++r) a += partials[r * 256 + t];
  tmp[t] = a;
  __syncthreads();
  if (t < 128) {
    float S = tmp[t], S2 = tmp[t + 128];
    float mean = S / (float)N_E;
    float var = S2 / (float)N_E - mean * mean;   // biased, matches reference
    float inv = rsqrtf(var + BN_EPS);
    float sc = gamma[t] * inv;
    scsh[t] = sc;
    scsh[t + 128] = beta[t] - mean * sc;
  }
}

template<bool USEWS>
__global__ __launch_bounds__(256) void applyK(const short* __restrict__ h,
                                              const float* __restrict__ scsh,
                                              float* out) {
  const int TOT4 = N_E * 128 / 4;
  int j0 = blockIdx.x * 256 + threadIdx.x;
  int c4 = j0 & 31;
  float4 sc = *(const float4*)(scsh + c4 * 4);
  float4 sh = *(const float4*)(scsh + 128 + c4 * 4);
  int stride = gridDim.x * 256;
  for (int j = j0; j < TOT4; j += stride) {
    float4 v;
    if (USEWS) {
      short4 s = *(const short4*)(h + (size_t)j * 4);
      v.x = bf2f((unsigned short)s.x) * sc.x + sh.x;
      v.y = bf2f((unsigned short)s.y) * sc.y + sh.y;
      v.z = bf2f((unsigned short)s.z) * sc.z + sh.z;
      v.w = bf2f((unsigned short)s.w) * sc.w + sh.w;
    } else {
      float4 hv = ((const float4*)out)[j];
      v.x = hv.x * sc.x + sh.x;
      v.y = hv.y * sc.y + sh.y;
      v.z = hv.z * sc.z + sh.z;
      v.w = hv.w * sc.w + sh.w;
    }
    ((float4*)out)[j] = v;
  }
}

extern "C" void kernel_launch(void* const* d_in, const int* in_sizes, int n_in,
                              void* d_out, int out_size, void* d_ws, size_t ws_size,
                              hipStream_t stream) {
  const float* nodef = (const float*)d_in[0];
  const float* edgef = (const float*)d_in[1];
  const int* srcI = (const int*)d_in[2];
  const int* dstI = (const int*)d_in[3];
  const float* W1 = (const float*)d_in[4];
  const float* b1 = (const float*)d_in[5];
  const float* W2 = (const float*)d_in[6];
  const float* b2 = (const float*)d_in[7];
  const float* W3 = (const float*)d_in[8];
  const float* b3 = (const float*)d_in[9];
  const float* gamma = (const float*)d_in[10];
  const float* beta = (const float*)d_in[11];
  float* out = (float*)d_out;
  char* ws = (char*)d_ws;

  float* partials = (float*)(ws + PART_OFF);
  float* scsh = (float*)(ws + SCALE_OFF);
  short* wt = (short*)(ws + WT_OFF);
  short* ybuf;
  short* h = nullptr;
  bool usews;
  if (ws_size >= (size_t)META_END + Y_BYTES + H_BYTES) {
    ybuf = (short*)(ws + META_END);
    h = (short*)(ws + META_END + Y_BYTES);
    usews = true;
  } else if (ws_size >= (size_t)META_END + H_BYTES) {
    h = (short*)(ws + META_END);
    ybuf = (short*)((char*)d_out + OUT_BYTES - Y_BYTES);  // tail of out; rewritten by applyK last
    usews = true;
  } else {
    ybuf = (short*)(ws + META_END);
    usews = false;
  }

  prepK<<<96, 256, 0, stream>>>(W1, W2, W3, wt, partials);
  nodeK<<<782, 256, 0, stream>>>(nodef, wt, ybuf);
  if (usews) {
    gnn2<true><<<GRID2, 512, 0, stream>>>(edgef, srcI, dstI, ybuf, b1, b2, b3,
                                          wt, partials, h, out);
  } else {
    gnn2<false><<<GRID2, 512, 0, stream>>>(edgef, srcI, dstI, ybuf, b1, b2, b3,
                                           wt, partials, h, out);
  }
  statsK<<<1, 256, 0, stream>>>(partials, gamma, beta, scsh);
  if (usews) {
    applyK<true><<<2048, 256, 0, stream>>>(h, scsh, out);
  } else {
    applyK<false><<<2048, 256, 0, stream>>>(h, scsh, out);
  }
}

// Round 6
// 213.712 us; speedup vs baseline: 1.2240x; 1.2240x over previous
//
#include <hip/hip_runtime.h>
#include <hip/hip_bf16.h>
#include <cstddef>

#define N_E 400000
#define N_V 50000
#define NEG_SLOPE 0.01f
#define BN_EPS 1e-5f
#define GRID2 512

typedef __attribute__((ext_vector_type(8))) short bf16x8;
typedef __attribute__((ext_vector_type(4))) float f32x4;

// ws layout (bytes)
#define PART_OFF   0            // 64 replicas * 256 f32 = 65536 B
#define SCALE_OFF  65536        // 256 f32 (scale[128], shift[128])
#define WT_OFF     66560        // bf16 weights, packed in MFMA A-frag chunks
// wt shorts: W1a 8192 @0 | W1b 16384 @8192 | W2 16384 @24576 | W3 16384 @40960
#define META_END   181248
#define Y_BYTES    12800000ULL  // 50000*128*2
#define H_BYTES    102400000ULL // 400000*128*2
#define OUT_BYTES  204800000ULL

__device__ __forceinline__ unsigned short f2bf(float f) {
  unsigned u = __builtin_bit_cast(unsigned, f);
  u += 0x7fffu + ((u >> 16) & 1u);            // RNE
  return (unsigned short)(u >> 16);
}
__device__ __forceinline__ float bf2f(unsigned short s) {
  return __builtin_bit_cast(float, (unsigned)s << 16);
}
__device__ __forceinline__ float lrelu(float x) {
  return x >= 0.f ? x : NEG_SLOPE * x;
}
// pack 2 f32 -> 2 bf16 (RNE), lo in low 16 bits
__device__ __forceinline__ unsigned pk2(float lo, float hi) {
  return (unsigned)f2bf(lo) | ((unsigned)f2bf(hi) << 16);
}
// elementwise add of 2 packed bf16 pairs
__device__ __forceinline__ int addbf(int a, int b) {
  unsigned ua = (unsigned)a, ub = (unsigned)b;
  float l = __builtin_bit_cast(float, ua << 16) + __builtin_bit_cast(float, ub << 16);
  float h = __builtin_bit_cast(float, ua & 0xffff0000u) +
            __builtin_bit_cast(float, ub & 0xffff0000u);
  return (int)pk2(l, h);
}

// MFMA over 4 edge-tiles, 1 feature-tile: D[feat][edge]
template<int KS>
__device__ __forceinline__ void runL(const short* sA, int stride, const bf16x8* fr,
                                     f32x4* acc, int lane) {
  const int col = lane & 15;
  const int kb = (lane >> 4) * 8;
  #pragma unroll
  for (int et = 0; et < 4; ++et) {
    const short* bp = sA + (et * 16 + col) * stride + kb;
    #pragma unroll
    for (int s = 0; s < KS; ++s) {
      bf16x8 b = *(const bf16x8*)(bp + s * 32);
      acc[et] = __builtin_amdgcn_mfma_f32_16x16x32_bf16(fr[s], b, acc[et], 0, 0, 0);
    }
  }
}

// epilogue: bias (+y for MODE1) + lrelu (+stats for MODE2) -> bf16 int2 into LDS
template<int MODE>
__device__ __forceinline__ void epiW(f32x4* acc, float4 bb, const short* sYb,
                                     short* dst, int f, int col,
                                     float* sE, float* sQ) {
  #pragma unroll
  for (int et = 0; et < 4; ++et) {
    const int edge = et * 16 + col;
    f32x4 a = acc[et];
    float v0 = a[0] + bb.x, v1 = a[1] + bb.y, v2 = a[2] + bb.z, v3 = a[3] + bb.w;
    if (MODE == 1) {
      short4 q = *(const short4*)(sYb + edge * 136 + f);
      v0 += bf2f((unsigned short)q.x); v1 += bf2f((unsigned short)q.y);
      v2 += bf2f((unsigned short)q.z); v3 += bf2f((unsigned short)q.w);
    }
    v0 = lrelu(v0); v1 = lrelu(v1); v2 = lrelu(v2); v3 = lrelu(v3);
    if (MODE == 2) {
      sE[0] += v0; sQ[0] += v0 * v0; sE[1] += v1; sQ[1] += v1 * v1;
      sE[2] += v2; sQ[2] += v2 * v2; sE[3] += v3; sQ[3] += v3 * v3;
    }
    *(int2*)(dst + edge * 136 + f) = make_int2((int)pk2(v0, v1), (int)pk2(v2, v3));
    acc[et] = (f32x4){0.f, 0.f, 0.f, 0.f};
  }
}

// ---- persistent edge-MLP kernel: 512 thr, 8 waves, 1 feature-tile/wave ----
// occupancy contract: 60KB LDS -> 2 blocks/CU = 16 waves/CU = 4 waves/EU.
// Pin waves_per_eu to (4,4) so the VGPR budget is 128 (not a squeezed 64 that
// spills the loop-carried staging regs to scratch -- round-5 WRITE_SIZE 342MB).
template<bool USEWS>
__global__ __launch_bounds__(512, 4) __attribute__((amdgpu_waves_per_eu(4, 4)))
void gnn2(
    const float* __restrict__ edgef, const int* __restrict__ srcI,
    const int* __restrict__ dstI, const short* __restrict__ ybuf,
    const float* __restrict__ b1, const float* __restrict__ b2,
    const float* __restrict__ b3, const short* __restrict__ wt,
    float* __restrict__ partials, short* __restrict__ hout,
    float* __restrict__ fout) {
  __shared__ short sX[64 * 72];    // ef tile bf16 (K=64), pad stride 72
  __shared__ short sY[64 * 136];   // ysum tile bf16
  __shared__ short sHa[64 * 136];  // h1 / h3
  __shared__ short sHb[64 * 136];  // h2

  const int tid = threadIdx.x;
  const int lane = tid & 63;
  const int w = tid >> 6;
  const int bid = blockIdx.x;
  const int r8 = tid >> 3, c8 = tid & 7;
  const int col = lane & 15;
  const int f = w * 16 + ((lane >> 4) << 2);

  bf16x8 fr1[2], fr2[4], fr3[4];
  #pragma unroll
  for (int s = 0; s < 2; ++s)
    fr1[s] = *(const bf16x8*)(wt + (((w * 2 + s) << 9) + lane * 8));
  #pragma unroll
  for (int s = 0; s < 4; ++s)
    fr2[s] = *(const bf16x8*)(wt + 24576 + (((w * 4 + s) << 9) + lane * 8));
  #pragma unroll
  for (int s = 0; s < 4; ++s)
    fr3[s] = *(const bf16x8*)(wt + 40960 + (((w * 4 + s) << 9) + lane * 8));

  const float4 bb1 = *(const float4*)(b1 + f);
  const float4 bb2 = *(const float4*)(b2 + f);
  const float4 bb3 = *(const float4*)(b3 + f);

  f32x4 acc[4];
  #pragma unroll
  for (int i = 0; i < 4; ++i) acc[i] = (f32x4){0.f, 0.f, 0.f, 0.f};
  float sE[4] = {0.f, 0.f, 0.f, 0.f}, sQ[4] = {0.f, 0.f, 0.f, 0.f};

  // prologue: stage tile `bid`
  {
    int e = bid * 64 + r8;
    int si = srcI[e], di = dstI[e];
    const float4* efp = (const float4*)(edgef + (size_t)e * 64) + c8 * 2;
    float4 ea = efp[0], eb = efp[1];
    const int4* yps = (const int4*)(ybuf + (size_t)si * 128) + c8 * 2;
    const int4* ypd = (const int4*)(ybuf + (size_t)di * 128) + c8 * 2;
    int4 a0 = yps[0], a1 = yps[1], d0 = ypd[0], d1 = ypd[1];
    int4 ex;
    ex.x = (int)pk2(ea.x, ea.y); ex.y = (int)pk2(ea.z, ea.w);
    ex.z = (int)pk2(eb.x, eb.y); ex.w = (int)pk2(eb.z, eb.w);
    *(int4*)(sX + r8 * 72 + c8 * 8) = ex;
    int4 y0, y1;
    y0.x = addbf(a0.x, d0.x); y0.y = addbf(a0.y, d0.y);
    y0.z = addbf(a0.z, d0.z); y0.w = addbf(a0.w, d0.w);
    y1.x = addbf(a1.x, d1.x); y1.y = addbf(a1.y, d1.y);
    y1.z = addbf(a1.z, d1.z); y1.w = addbf(a1.w, d1.w);
    *(int4*)(sY + r8 * 136 + c8 * 16) = y0;
    *(int4*)(sY + r8 * 136 + c8 * 16 + 8) = y1;
  }
  __syncthreads();

  for (int t = bid; t < N_E / 64; t += GRID2) {
    const int tn = t + GRID2;
    const bool pf = tn < N_E / 64;
    int si = 0, di = 0;
    float4 ea, eb;
    // ---- L1 (K=64) + issue next-tile idx/ef loads ----
    runL<2>(sX, 72, fr1, acc, lane);
    if (pf) {
      int e = tn * 64 + r8;
      si = srcI[e]; di = dstI[e];
      const float4* efp = (const float4*)(edgef + (size_t)e * 64) + c8 * 2;
      ea = efp[0]; eb = efp[1];
    }
    epiW<1>(acc, bb1, sY, sHa, f, col, sE, sQ);
    __syncthreads();
    // ---- L2 + issue next-tile y gathers ----
    runL<4>(sHa, 136, fr2, acc, lane);
    int4 a0, a1, d0, d1;
    if (pf) {
      const int4* yps = (const int4*)(ybuf + (size_t)si * 128) + c8 * 2;
      const int4* ypd = (const int4*)(ybuf + (size_t)di * 128) + c8 * 2;
      a0 = yps[0]; a1 = yps[1]; d0 = ypd[0]; d1 = ypd[1];
    }
    epiW<0>(acc, bb2, sY, sHb, f, col, sE, sQ);
    // fold src+dst now: halves barrier-crossing liveness (16 -> 8 regs)
    int4 y0, y1;
    if (pf) {
      y0.x = addbf(a0.x, d0.x); y0.y = addbf(a0.y, d0.y);
      y0.z = addbf(a0.z, d0.z); y0.w = addbf(a0.w, d0.w);
      y1.x = addbf(a1.x, d1.x); y1.y = addbf(a1.y, d1.y);
      y1.z = addbf(a1.z, d1.z); y1.w = addbf(a1.w, d1.w);
    }
    __syncthreads();
    // ---- L3 + stats + LDS-write next tile ----
    runL<4>(sHb, 136, fr3, acc, lane);
    epiW<2>(acc, bb3, sY, sHa, f, col, sE, sQ);
    if (pf) {
      int4 ex;
      ex.x = (int)pk2(ea.x, ea.y); ex.y = (int)pk2(ea.z, ea.w);
      ex.z = (int)pk2(eb.x, eb.y); ex.w = (int)pk2(eb.z, eb.w);
      *(int4*)(sX + r8 * 72 + c8 * 8) = ex;
      *(int4*)(sY + r8 * 136 + c8 * 16) = y0;
      *(int4*)(sY + r8 * 136 + c8 * 16 + 8) = y1;
    }
    __syncthreads();
    // ---- out: h3 tile -> global (coalesced) ----
    if (USEWS) {
      int4* dst = (int4*)(hout + (size_t)t * 8192);
      #pragma unroll
      for (int j = 0; j < 2; ++j)
        dst[r8 * 16 + c8 * 2 + j] = *(const int4*)(sHa + r8 * 136 + c8 * 16 + j * 8);
    } else {
      float4* dst = (float4*)(fout + (size_t)t * 8192);
      #pragma unroll
      for (int j = 0; j < 2; ++j) {
        int4 tv = *(const int4*)(sHa + r8 * 136 + c8 * 16 + j * 8);
        float4 o0, o1;
        o0.x = bf2f((unsigned short)((unsigned)tv.x & 0xffffu));
        o0.y = bf2f((unsigned short)((unsigned)tv.x >> 16));
        o0.z = bf2f((unsigned short)((unsigned)tv.y & 0xffffu));
        o0.w = bf2f((unsigned short)((unsigned)tv.y >> 16));
        o1.x = bf2f((unsigned short)((unsigned)tv.z & 0xffffu));
        o1.y = bf2f((unsigned short)((unsigned)tv.z >> 16));
        o1.z = bf2f((unsigned short)((unsigned)tv.w & 0xffffu));
        o1.w = bf2f((unsigned short)((unsigned)tv.w >> 16));
        dst[r8 * 32 + c8 * 4 + j * 2] = o0;
        dst[r8 * 32 + c8 * 4 + j * 2 + 1] = o1;
      }
    }
    __syncthreads();
  }

  // stats flush: butterfly over edge lanes then one atomic set per block
  #pragma unroll
  for (int m = 1; m <= 8; m <<= 1) {
    #pragma unroll
    for (int i = 0; i < 4; ++i) {
      sE[i] += __shfl_xor(sE[i], m, 64);
      sQ[i] += __shfl_xor(sQ[i], m, 64);
    }
  }
  if ((lane & 15) == 0) {
    float* pp = partials + (bid & 63) * 256;
    #pragma unroll
    for (int i = 0; i < 4; ++i) {
      atomicAdd(&pp[f + i], sE[i]);
      atomicAdd(&pp[128 + f + i], sQ[i]);
    }
  }
}

// ---- per-node precompute: y = nf * W1b  (bf16 out) ----
__global__ __launch_bounds__(256) void nodeK(const float* __restrict__ nodef,
                                             const short* __restrict__ wt,
                                             short* __restrict__ y) {
  __shared__ short sN[64 * 136];
  const int tid = threadIdx.x;
  const int lane = tid & 63;
  const int w = tid >> 6;
  const int n0 = blockIdx.x * 64;
  const int r = tid >> 2, p4 = tid & 3;
  {
    int v = n0 + r;
    int vc = v < N_V ? v : N_V - 1;
    const float4* np = (const float4*)(nodef + (size_t)vc * 128) + p4 * 8;
    #pragma unroll
    for (int j = 0; j < 8; ++j) {
      float4 a = np[j];
      *(int2*)(sN + r * 136 + p4 * 32 + j * 4) =
          make_int2((int)pk2(a.x, a.y), (int)pk2(a.z, a.w));
    }
  }
  __syncthreads();
  const short* wb = wt + 8192;
  bf16x8 fr[8];
  #pragma unroll
  for (int nt = 0; nt < 2; ++nt)
    #pragma unroll
    for (int s = 0; s < 4; ++s)
      fr[nt * 4 + s] = *(const bf16x8*)(wb + ((((w * 2 + nt) * 4 + s) << 9) + lane * 8));
  f32x4 acc[8];
  #pragma unroll
  for (int i = 0; i < 8; ++i) acc[i] = (f32x4){0.f, 0.f, 0.f, 0.f};
  const int col = lane & 15;
  const int kb = (lane >> 4) * 8;
  #pragma unroll
  for (int et = 0; et < 4; ++et) {
    const short* bp = sN + (et * 16 + col) * 136 + kb;
    #pragma unroll
    for (int s = 0; s < 4; ++s) {
      bf16x8 b = *(const bf16x8*)(bp + s * 32);
      acc[0 + et] = __builtin_amdgcn_mfma_f32_16x16x32_bf16(fr[s], b, acc[0 + et], 0, 0, 0);
      acc[4 + et] = __builtin_amdgcn_mfma_f32_16x16x32_bf16(fr[4 + s], b, acc[4 + et], 0, 0, 0);
    }
  }
  __syncthreads();   // sN input reads done
  {
    const int fb = (lane >> 4) * 4;
    #pragma unroll
    for (int nt = 0; nt < 2; ++nt) {
      const int f0 = w * 32 + nt * 16 + fb;
      #pragma unroll
      for (int et = 0; et < 4; ++et) {
        f32x4 a = acc[nt * 4 + et];
        *(int2*)(sN + (et * 16 + col) * 136 + f0) =
            make_int2((int)pk2(a[0], a[1]), (int)pk2(a[2], a[3]));
      }
    }
  }
  __syncthreads();
  if (n0 + r < N_V) {
    #pragma unroll
    for (int j = 0; j < 4; ++j) {   // 4 int4 = 32 shorts per thread
      int4 tv = *(const int4*)(sN + r * 136 + p4 * 32 + j * 8);
      *(int4*)(y + (size_t)(n0 + r) * 128 + p4 * 32 + j * 8) = tv;
    }
  }
}

// ---- weight pack + partials zero ----
__global__ __launch_bounds__(256) void prepK(const float* __restrict__ W1,
                                             const float* __restrict__ W2,
                                             const float* __restrict__ W3,
                                             short* __restrict__ wt,
                                             float* __restrict__ partials) {
  int b = blockIdx.x, t = threadIdx.x;
  if (b < 64) { partials[b * 256 + t] = 0.f; return; }
  int g = (b - 64) * 256 + t;
  for (int fi = g; fi < 57344; fi += 32 * 256) {
    float val;
    if (fi < 8192) {                       // W1a: 8 tiles x 2 ksteps (K=64)
      int c = fi >> 9, r = fi & 511;
      int l = r >> 3, j = r & 7;
      int tt = c >> 1, s = c & 1;
      int n = tt * 16 + (l & 15);
      int k = s * 32 + (l >> 4) * 8 + j;
      val = W1[k * 128 + n];
    } else if (fi < 24576) {               // W1b: 8 tiles x 4 ksteps (rows 64..191)
      int f2 = fi - 8192;
      int c = f2 >> 9, r = f2 & 511;
      int l = r >> 3, j = r & 7;
      int tt = c >> 2, s = c & 3;
      int n = tt * 16 + (l & 15);
      int k = s * 32 + (l >> 4) * 8 + j;
      val = W1[(64 + k) * 128 + n];
    } else if (fi < 40960) {               // W2
      int f2 = fi - 24576;
      int c = f2 >> 9, r = f2 & 511;
      int l = r >> 3, j = r & 7;
      int tt = c >> 2, s = c & 3;
      int n = tt * 16 + (l & 15);
      int k = s * 32 + (l >> 4) * 8 + j;
      val = W2[k * 128 + n];
    } else {                               // W3
      int f3 = fi - 40960;
      int c = f3 >> 9, r = f3 & 511;
      int l = r >> 3, j = r & 7;
      int tt = c >> 2, s = c & 3;
      int n = tt * 16 + (l & 15);
      int k = s * 32 + (l >> 4) * 8 + j;
      val = W3[k * 128 + n];
    }
    wt[fi] = (short)f2bf(val);
  }
}

__global__ __launch_bounds__(256) void statsK(const float* __restrict__ partials,
                                              const float* __restrict__ gamma,
                                              const float* __restrict__ beta,
                                              float* __restrict__ scsh) {
  __shared__ float tmp[256];
  int t = threadIdx.x;
  float a = 0.f;
  #pragma unroll 8
  for (int r = 0; r < 64; ++r) a += partials[r * 256 + t];
  tmp[t] = a;
  __syncthreads();
  if (t < 128) {
    float S = tmp[t], S2 = tmp[t + 128];
    float mean = S / (float)N_E;
    float var = S2 / (float)N_E - mean * mean;   // biased, matches reference
    float inv = rsqrtf(var + BN_EPS);
    float sc = gamma[t] * inv;
    scsh[t] = sc;
    scsh[t + 128] = beta[t] - mean * sc;
  }
}

template<bool USEWS>
__global__ __launch_bounds__(256) void applyK(const short* __restrict__ h,
                                              const float* __restrict__ scsh,
                                              float* out) {
  const int TOT4 = N_E * 128 / 4;
  int j0 = blockIdx.x * 256 + threadIdx.x;
  int c4 = j0 & 31;
  float4 sc = *(const float4*)(scsh + c4 * 4);
  float4 sh = *(const float4*)(scsh + 128 + c4 * 4);
  int stride = gridDim.x * 256;
  for (int j = j0; j < TOT4; j += stride) {
    float4 v;
    if (USEWS) {
      short4 s = *(const short4*)(h + (size_t)j * 4);
      v.x = bf2f((unsigned short)s.x) * sc.x + sh.x;
      v.y = bf2f((unsigned short)s.y) * sc.y + sh.y;
      v.z = bf2f((unsigned short)s.z) * sc.z + sh.z;
      v.w = bf2f((unsigned short)s.w) * sc.w + sh.w;
    } else {
      float4 hv = ((const float4*)out)[j];
      v.x = hv.x * sc.x + sh.x;
      v.y = hv.y * sc.y + sh.y;
      v.z = hv.z * sc.z + sh.z;
      v.w = hv.w * sc.w + sh.w;
    }
    ((float4*)out)[j] = v;
  }
}

extern "C" void kernel_launch(void* const* d_in, const int* in_sizes, int n_in,
                              void* d_out, int out_size, void* d_ws, size_t ws_size,
                              hipStream_t stream) {
  const float* nodef = (const float*)d_in[0];
  const float* edgef = (const float*)d_in[1];
  const int* srcI = (const int*)d_in[2];
  const int* dstI = (const int*)d_in[3];
  const float* W1 = (const float*)d_in[4];
  const float* b1 = (const float*)d_in[5];
  const float* W2 = (const float*)d_in[6];
  const float* b2 = (const float*)d_in[7];
  const float* W3 = (const float*)d_in[8];
  const float* b3 = (const float*)d_in[9];
  const float* gamma = (const float*)d_in[10];
  const float* beta = (const float*)d_in[11];
  float* out = (float*)d_out;
  char* ws = (char*)d_ws;

  float* partials = (float*)(ws + PART_OFF);
  float* scsh = (float*)(ws + SCALE_OFF);
  short* wt = (short*)(ws + WT_OFF);
  short* ybuf;
  short* h = nullptr;
  bool usews;
  if (ws_size >= (size_t)META_END + Y_BYTES + H_BYTES) {
    ybuf = (short*)(ws + META_END);
    h = (short*)(ws + META_END + Y_BYTES);
    usews = true;
  } else if (ws_size >= (size_t)META_END + H_BYTES) {
    h = (short*)(ws + META_END);
    ybuf = (short*)((char*)d_out + OUT_BYTES - Y_BYTES);  // tail of out; rewritten by applyK last
    usews = true;
  } else {
    ybuf = (short*)(ws + META_END);
    usews = false;
  }

  prepK<<<96, 256, 0, stream>>>(W1, W2, W3, wt, partials);
  nodeK<<<782, 256, 0, stream>>>(nodef, wt, ybuf);
  if (usews) {
    gnn2<true><<<GRID2, 512, 0, stream>>>(edgef, srcI, dstI, ybuf, b1, b2, b3,
                                          wt, partials, h, out);
  } else {
    gnn2<false><<<GRID2, 512, 0, stream>>>(edgef, srcI, dstI, ybuf, b1, b2, b3,
                                           wt, partials, h, out);
  }
  statsK<<<1, 256, 0, stream>>>(partials, gamma, beta, scsh);
  if (usews) {
    applyK<true><<<2048, 256, 0, stream>>>(h, scsh, out);
  } else {
    applyK<false><<<2048, 256, 0, stream>>>(h, scsh, out);
  }
}

// Round 7
// 210.954 us; speedup vs baseline: 1.2401x; 1.0131x over previous
//
#include <hip/hip_runtime.h>
#include <hip/hip_bf16.h>
#include <cstddef>

#define N_E 400000
#define N_V 50000
#define NEG_SLOPE 0.01f
#define BN_EPS 1e-5f
#define GRID2 512
#define NT (N_E / 64)

typedef __attribute__((ext_vector_type(8))) short bf16x8;
typedef __attribute__((ext_vector_type(4))) float f32x4;

// ws layout (bytes)
#define PART_OFF   0            // 64 replicas * 256 f32 = 65536 B
#define SCALE_OFF  65536        // 256 f32 (scale[128], shift[128])
#define WT_OFF     66560        // bf16 weights, packed in MFMA A-frag chunks
// wt shorts: W1a 8192 @0 | W1b 16384 @8192 | W2 16384 @24576 | W3 16384 @40960
#define META_END   181248
#define Y_BYTES    12800000ULL  // 50000*128*2
#define H_BYTES    102400000ULL // 400000*128*2
#define OUT_BYTES  204800000ULL

__device__ __forceinline__ unsigned short f2bf(float f) {
  unsigned u = __builtin_bit_cast(unsigned, f);
  u += 0x7fffu + ((u >> 16) & 1u);            // RNE
  return (unsigned short)(u >> 16);
}
__device__ __forceinline__ float bf2f(unsigned short s) {
  return __builtin_bit_cast(float, (unsigned)s << 16);
}
__device__ __forceinline__ float lrelu(float x) {
  return x >= 0.f ? x : NEG_SLOPE * x;
}
// pack 2 f32 -> 2 bf16 (RNE), lo in low 16 bits
__device__ __forceinline__ unsigned pk2(float lo, float hi) {
  return (unsigned)f2bf(lo) | ((unsigned)f2bf(hi) << 16);
}
// elementwise add of 2 packed bf16 pairs
__device__ __forceinline__ int addbf(int a, int b) {
  unsigned ua = (unsigned)a, ub = (unsigned)b;
  float l = __builtin_bit_cast(float, ua << 16) + __builtin_bit_cast(float, ub << 16);
  float h = __builtin_bit_cast(float, ua & 0xffff0000u) +
            __builtin_bit_cast(float, ub & 0xffff0000u);
  return (int)pk2(l, h);
}

// MFMA over 4 edge-tiles, 1 feature-tile: D[feat][edge]
template<int KS>
__device__ __forceinline__ void runL(const short* sA, int stride, const bf16x8* fr,
                                     f32x4* acc, int lane) {
  const int col = lane & 15;
  const int kb = (lane >> 4) * 8;
  #pragma unroll
  for (int et = 0; et < 4; ++et) {
    const short* bp = sA + (et * 16 + col) * stride + kb;
    #pragma unroll
    for (int s = 0; s < KS; ++s) {
      bf16x8 b = *(const bf16x8*)(bp + s * 32);
      acc[et] = __builtin_amdgcn_mfma_f32_16x16x32_bf16(fr[s], b, acc[et], 0, 0, 0);
    }
  }
}

// epilogue: LDS bias (+y for MODE1) + lrelu (+stats for MODE2) -> bf16 int2 into LDS
template<int MODE>
__device__ __forceinline__ void epiW(f32x4* acc, const float* sBias, const short* sYb,
                                     short* dst, int f, int col,
                                     float* sE, float* sQ) {
  float4 bb = *(const float4*)(sBias + f);   // LDS read; barriers keep it in-loop
  #pragma unroll
  for (int et = 0; et < 4; ++et) {
    const int edge = et * 16 + col;
    f32x4 a = acc[et];
    float v0 = a[0] + bb.x, v1 = a[1] + bb.y, v2 = a[2] + bb.z, v3 = a[3] + bb.w;
    if (MODE == 1) {
      short4 q = *(const short4*)(sYb + edge * 136 + f);
      v0 += bf2f((unsigned short)q.x); v1 += bf2f((unsigned short)q.y);
      v2 += bf2f((unsigned short)q.z); v3 += bf2f((unsigned short)q.w);
    }
    v0 = lrelu(v0); v1 = lrelu(v1); v2 = lrelu(v2); v3 = lrelu(v3);
    if (MODE == 2) {
      sE[0] += v0; sQ[0] += v0 * v0; sE[1] += v1; sQ[1] += v1 * v1;
      sE[2] += v2; sQ[2] += v2 * v2; sE[3] += v3; sQ[3] += v3 * v3;
    }
    *(int2*)(dst + edge * 136 + f) = make_int2((int)pk2(v0, v1), (int)pk2(v2, v3));
    acc[et] = (f32x4){0.f, 0.f, 0.f, 0.f};
  }
}

// ---- persistent edge-MLP kernel: 512 thr, 8 waves, 1 feature-tile/wave ----
// occupancy contract: ~62KB LDS -> 2 blocks/CU = 16 waves/CU = 4 waves/EU.
// Pure-attribute form (no __launch_bounds__): pins waves/EU to 4 so the VGPR
// budget is 128. Round-5/6: launch_bounds path left the allocator at 64 regs
// and spilled the loop-carried staging (WRITE_SIZE 342/195MB vs 102 expected).
template<bool USEWS>
__global__ __attribute__((amdgpu_flat_work_group_size(512, 512),
                          amdgpu_waves_per_eu(4, 4)))
void gnn2(
    const float* __restrict__ edgef, const int* __restrict__ srcI,
    const int* __restrict__ dstI, const short* __restrict__ ybuf,
    const float* __restrict__ b1, const float* __restrict__ b2,
    const float* __restrict__ b3, const short* __restrict__ wt,
    float* __restrict__ partials, short* __restrict__ hout,
    float* __restrict__ fout) {
  __shared__ short sX[64 * 72];    // ef tile bf16 (K=64), pad stride 72
  __shared__ short sY[64 * 136];   // ysum tile bf16
  __shared__ short sHa[64 * 136];  // h1 / h3
  __shared__ short sHb[64 * 136];  // h2
  __shared__ float sB[384];        // b1|b2|b3

  const int tid = threadIdx.x;
  const int lane = tid & 63;
  const int w = tid >> 6;
  const int bid = blockIdx.x;
  const int r8 = tid >> 3, c8 = tid & 7;
  const int col = lane & 15;
  const int f = w * 16 + ((lane >> 4) << 2);

  bf16x8 fr1[2], fr2[4], fr3[4];
  #pragma unroll
  for (int s = 0; s < 2; ++s)
    fr1[s] = *(const bf16x8*)(wt + (((w * 2 + s) << 9) + lane * 8));
  #pragma unroll
  for (int s = 0; s < 4; ++s)
    fr2[s] = *(const bf16x8*)(wt + 24576 + (((w * 4 + s) << 9) + lane * 8));
  #pragma unroll
  for (int s = 0; s < 4; ++s)
    fr3[s] = *(const bf16x8*)(wt + 40960 + (((w * 4 + s) << 9) + lane * 8));

  if (tid < 384)
    sB[tid] = (tid < 128) ? b1[tid] : (tid < 256) ? b2[tid - 128] : b3[tid - 256];

  f32x4 acc[4];
  #pragma unroll
  for (int i = 0; i < 4; ++i) acc[i] = (f32x4){0.f, 0.f, 0.f, 0.f};
  float sE[4] = {0.f, 0.f, 0.f, 0.f}, sQ[4] = {0.f, 0.f, 0.f, 0.f};

  // prologue: stage tile `bid`
  {
    int e = bid * 64 + r8;
    int si = srcI[e], di = dstI[e];
    const float4* efp = (const float4*)(edgef + (size_t)e * 64) + c8 * 2;
    float4 ea = efp[0], eb = efp[1];
    const int4* yps = (const int4*)(ybuf + (size_t)si * 128) + c8 * 2;
    const int4* ypd = (const int4*)(ybuf + (size_t)di * 128) + c8 * 2;
    int4 a0 = yps[0], a1 = yps[1], d0 = ypd[0], d1 = ypd[1];
    int4 ex;
    ex.x = (int)pk2(ea.x, ea.y); ex.y = (int)pk2(ea.z, ea.w);
    ex.z = (int)pk2(eb.x, eb.y); ex.w = (int)pk2(eb.z, eb.w);
    *(int4*)(sX + r8 * 72 + c8 * 8) = ex;
    int4 y0, y1;
    y0.x = addbf(a0.x, d0.x); y0.y = addbf(a0.y, d0.y);
    y0.z = addbf(a0.z, d0.z); y0.w = addbf(a0.w, d0.w);
    y1.x = addbf(a1.x, d1.x); y1.y = addbf(a1.y, d1.y);
    y1.z = addbf(a1.z, d1.z); y1.w = addbf(a1.w, d1.w);
    *(int4*)(sY + r8 * 136 + c8 * 16) = y0;
    *(int4*)(sY + r8 * 136 + c8 * 16 + 8) = y1;
  }
  __syncthreads();

  for (int t = bid; t < NT; t += GRID2) {
    const int tn = t + GRID2;
    const bool pf = tn < NT;
    // ---- A: L1 (K=64); issue next-tile idx + y gathers ----
    runL<2>(sX, 72, fr1, acc, lane);
    int4 a0, a1, d0, d1;
    if (pf) {
      int e = tn * 64 + r8;
      int si = srcI[e], di = dstI[e];
      const int4* yps = (const int4*)(ybuf + (size_t)si * 128) + c8 * 2;
      const int4* ypd = (const int4*)(ybuf + (size_t)di * 128) + c8 * 2;
      a0 = yps[0]; a1 = yps[1]; d0 = ypd[0]; d1 = ypd[1];
    }
    epiW<1>(acc, sB, sY, sHa, f, col, sE, sQ);
    __syncthreads();                 // (1)  [y regs cross: 16]
    // ---- B: L2; fold+write y into sY (free since (1)); issue ef loads ----
    runL<4>(sHa, 136, fr2, acc, lane);
    float4 ea, eb;
    if (pf) {
      int4 y0, y1;
      y0.x = addbf(a0.x, d0.x); y0.y = addbf(a0.y, d0.y);
      y0.z = addbf(a0.z, d0.z); y0.w = addbf(a0.w, d0.w);
      y1.x = addbf(a1.x, d1.x); y1.y = addbf(a1.y, d1.y);
      y1.z = addbf(a1.z, d1.z); y1.w = addbf(a1.w, d1.w);
      *(int4*)(sY + r8 * 136 + c8 * 16) = y0;
      *(int4*)(sY + r8 * 136 + c8 * 16 + 8) = y1;
      const float4* efp = (const float4*)(edgef + (size_t)(tn * 64 + r8) * 64) + c8 * 2;
      ea = efp[0]; eb = efp[1];
    }
    epiW<0>(acc, sB + 128, sY, sHb, f, col, sE, sQ);
    __syncthreads();                 // (2)  [ef regs cross: 8]
    // ---- C: L3; convert+write ef into sX (free since (1)); stats ----
    runL<4>(sHb, 136, fr3, acc, lane);
    if (pf) {
      int4 ex;
      ex.x = (int)pk2(ea.x, ea.y); ex.y = (int)pk2(ea.z, ea.w);
      ex.z = (int)pk2(eb.x, eb.y); ex.w = (int)pk2(eb.z, eb.w);
      *(int4*)(sX + r8 * 72 + c8 * 8) = ex;
    }
    epiW<2>(acc, sB + 256, sY, sHa, f, col, sE, sQ);
    __syncthreads();                 // (3)
    // ---- D: h3 tile -> global (coalesced) ----
    if (USEWS) {
      int4* dst = (int4*)(hout + (size_t)t * 8192);
      #pragma unroll
      for (int j = 0; j < 2; ++j)
        dst[r8 * 16 + c8 * 2 + j] = *(const int4*)(sHa + r8 * 136 + c8 * 16 + j * 8);
    } else {
      float4* dst = (float4*)(fout + (size_t)t * 8192);
      #pragma unroll
      for (int j = 0; j < 2; ++j) {
        int4 tv = *(const int4*)(sHa + r8 * 136 + c8 * 16 + j * 8);
        float4 o0, o1;
        o0.x = bf2f((unsigned short)((unsigned)tv.x & 0xffffu));
        o0.y = bf2f((unsigned short)((unsigned)tv.x >> 16));
        o0.z = bf2f((unsigned short)((unsigned)tv.y & 0xffffu));
        o0.w = bf2f((unsigned short)((unsigned)tv.y >> 16));
        o1.x = bf2f((unsigned short)((unsigned)tv.z & 0xffffu));
        o1.y = bf2f((unsigned short)((unsigned)tv.z >> 16));
        o1.z = bf2f((unsigned short)((unsigned)tv.w & 0xffffu));
        o1.w = bf2f((unsigned short)((unsigned)tv.w >> 16));
        dst[r8 * 32 + c8 * 4 + j * 2] = o0;
        dst[r8 * 32 + c8 * 4 + j * 2 + 1] = o1;
      }
    }
    __syncthreads();                 // (4)
  }

  // stats flush: butterfly over edge lanes then one atomic set per block
  #pragma unroll
  for (int m = 1; m <= 8; m <<= 1) {
    #pragma unroll
    for (int i = 0; i < 4; ++i) {
      sE[i] += __shfl_xor(sE[i], m, 64);
      sQ[i] += __shfl_xor(sQ[i], m, 64);
    }
  }
  if ((lane & 15) == 0) {
    float* pp = partials + (bid & 63) * 256;
    #pragma unroll
    for (int i = 0; i < 4; ++i) {
      atomicAdd(&pp[f + i], sE[i]);
      atomicAdd(&pp[128 + f + i], sQ[i]);
    }
  }
}

// ---- per-node precompute: y = nf * W1b  (bf16 out) ----
__global__ __launch_bounds__(256) void nodeK(const float* __restrict__ nodef,
                                             const short* __restrict__ wt,
                                             short* __restrict__ y) {
  __shared__ short sN[64 * 136];
  const int tid = threadIdx.x;
  const int lane = tid & 63;
  const int w = tid >> 6;
  const int n0 = blockIdx.x * 64;
  const int r = tid >> 2, p4 = tid & 3;
  {
    int v = n0 + r;
    int vc = v < N_V ? v : N_V - 1;
    const float4* np = (const float4*)(nodef + (size_t)vc * 128) + p4 * 8;
    #pragma unroll
    for (int j = 0; j < 8; ++j) {
      float4 a = np[j];
      *(int2*)(sN + r * 136 + p4 * 32 + j * 4) =
          make_int2((int)pk2(a.x, a.y), (int)pk2(a.z, a.w));
    }
  }
  __syncthreads();
  const short* wb = wt + 8192;
  bf16x8 fr[8];
  #pragma unroll
  for (int nt = 0; nt < 2; ++nt)
    #pragma unroll
    for (int s = 0; s < 4; ++s)
      fr[nt * 4 + s] = *(const bf16x8*)(wb + ((((w * 2 + nt) * 4 + s) << 9) + lane * 8));
  f32x4 acc[8];
  #pragma unroll
  for (int i = 0; i < 8; ++i) acc[i] = (f32x4){0.f, 0.f, 0.f, 0.f};
  const int col = lane & 15;
  const int kb = (lane >> 4) * 8;
  #pragma unroll
  for (int et = 0; et < 4; ++et) {
    const short* bp = sN + (et * 16 + col) * 136 + kb;
    #pragma unroll
    for (int s = 0; s < 4; ++s) {
      bf16x8 b = *(const bf16x8*)(bp + s * 32);
      acc[0 + et] = __builtin_amdgcn_mfma_f32_16x16x32_bf16(fr[s], b, acc[0 + et], 0, 0, 0);
      acc[4 + et] = __builtin_amdgcn_mfma_f32_16x16x32_bf16(fr[4 + s], b, acc[4 + et], 0, 0, 0);
    }
  }
  __syncthreads();   // sN input reads done
  {
    const int fb = (lane >> 4) * 4;
    #pragma unroll
    for (int nt = 0; nt < 2; ++nt) {
      const int f0 = w * 32 + nt * 16 + fb;
      #pragma unroll
      for (int et = 0; et < 4; ++et) {
        f32x4 a = acc[nt * 4 + et];
        *(int2*)(sN + (et * 16 + col) * 136 + f0) =
            make_int2((int)pk2(a[0], a[1]), (int)pk2(a[2], a[3]));
      }
    }
  }
  __syncthreads();
  if (n0 + r < N_V) {
    #pragma unroll
    for (int j = 0; j < 4; ++j) {   // 4 int4 = 32 shorts per thread
      int4 tv = *(const int4*)(sN + r * 136 + p4 * 32 + j * 8);
      *(int4*)(y + (size_t)(n0 + r) * 128 + p4 * 32 + j * 8) = tv;
    }
  }
}

// ---- weight pack + partials zero ----
__global__ __launch_bounds__(256) void prepK(const float* __restrict__ W1,
                                             const float* __restrict__ W2,
                                             const float* __restrict__ W3,
                                             short* __restrict__ wt,
                                             float* __restrict__ partials) {
  int b = blockIdx.x, t = threadIdx.x;
  if (b < 64) { partials[b * 256 + t] = 0.f; return; }
  int g = (b - 64) * 256 + t;
  for (int fi = g; fi < 57344; fi += 32 * 256) {
    float val;
    if (fi < 8192) {                       // W1a: 8 tiles x 2 ksteps (K=64)
      int c = fi >> 9, r = fi & 511;
      int l = r >> 3, j = r & 7;
      int tt = c >> 1, s = c & 1;
      int n = tt * 16 + (l & 15);
      int k = s * 32 + (l >> 4) * 8 + j;
      val = W1[k * 128 + n];
    } else if (fi < 24576) {               // W1b: 8 tiles x 4 ksteps (rows 64..191)
      int f2 = fi - 8192;
      int c = f2 >> 9, r = f2 & 511;
      int l = r >> 3, j = r & 7;
      int tt = c >> 2, s = c & 3;
      int n = tt * 16 + (l & 15);
      int k = s * 32 + (l >> 4) * 8 + j;
      val = W1[(64 + k) * 128 + n];
    } else if (fi < 40960) {               // W2
      int f2 = fi - 24576;
      int c = f2 >> 9, r = f2 & 511;
      int l = r >> 3, j = r & 7;
      int tt = c >> 2, s = c & 3;
      int n = tt * 16 + (l & 15);
      int k = s * 32 + (l >> 4) * 8 + j;
      val = W2[k * 128 + n];
    } else {                               // W3
      int f3 = fi - 40960;
      int c = f3 >> 9, r = f3 & 511;
      int l = r >> 3, j = r & 7;
      int tt = c >> 2, s = c & 3;
      int n = tt * 16 + (l & 15);
      int k = s * 32 + (l >> 4) * 8 + j;
      val = W3[k * 128 + n];
    }
    wt[fi] = (short)f2bf(val);
  }
}

__global__ __launch_bounds__(256) void statsK(const float* __restrict__ partials,
                                              const float* __restrict__ gamma,
                                              const float* __restrict__ beta,
                                              float* __restrict__ scsh) {
  __shared__ float tmp[256];
  int t = threadIdx.x;
  float a = 0.f;
  #pragma unroll 8
  for (int r = 0; r < 64; ++r) a += partials[r * 256 + t];
  tmp[t] = a;
  __syncthreads();
  if (t < 128) {
    float S = tmp[t], S2 = tmp[t + 128];
    float mean = S / (float)N_E;
    float var = S2 / (float)N_E - mean * mean;   // biased, matches reference
    float inv = rsqrtf(var + BN_EPS);
    float sc = gamma[t] * inv;
    scsh[t] = sc;
    scsh[t + 128] = beta[t] - mean * sc;
  }
}

template<bool USEWS>
__global__ __launch_bounds__(256) void applyK(const short* __restrict__ h,
                                              const float* __restrict__ scsh,
                                              float* out) {
  const int TOT4 = N_E * 128 / 4;
  int j0 = blockIdx.x * 256 + threadIdx.x;
  int c4 = j0 & 31;
  float4 sc = *(const float4*)(scsh + c4 * 4);
  float4 sh = *(const float4*)(scsh + 128 + c4 * 4);
  int stride = gridDim.x * 256;
  for (int j = j0; j < TOT4; j += stride) {
    float4 v;
    if (USEWS) {
      short4 s = *(const short4*)(h + (size_t)j * 4);
      v.x = bf2f((unsigned short)s.x) * sc.x + sh.x;
      v.y = bf2f((unsigned short)s.y) * sc.y + sh.y;
      v.z = bf2f((unsigned short)s.z) * sc.z + sh.z;
      v.w = bf2f((unsigned short)s.w) * sc.w + sh.w;
    } else {
      float4 hv = ((const float4*)out)[j];
      v.x = hv.x * sc.x + sh.x;
      v.y = hv.y * sc.y + sh.y;
      v.z = hv.z * sc.z + sh.z;
      v.w = hv.w * sc.w + sh.w;
    }
    ((float4*)out)[j] = v;
  }
}

extern "C" void kernel_launch(void* const* d_in, const int* in_sizes, int n_in,
                              void* d_out, int out_size, void* d_ws, size_t ws_size,
                              hipStream_t stream) {
  const float* nodef = (const float*)d_in[0];
  const float* edgef = (const float*)d_in[1];
  const int* srcI = (const int*)d_in[2];
  const int* dstI = (const int*)d_in[3];
  const float* W1 = (const float*)d_in[4];
  const float* b1 = (const float*)d_in[5];
  const float* W2 = (const float*)d_in[6];
  const float* b2 = (const float*)d_in[7];
  const float* W3 = (const float*)d_in[8];
  const float* b3 = (const float*)d_in[9];
  const float* gamma = (const float*)d_in[10];
  const float* beta = (const float*)d_in[11];
  float* out = (float*)d_out;
  char* ws = (char*)d_ws;

  float* partials = (float*)(ws + PART_OFF);
  float* scsh = (float*)(ws + SCALE_OFF);
  short* wt = (short*)(ws + WT_OFF);
  short* ybuf;
  short* h = nullptr;
  bool usews;
  if (ws_size >= (size_t)META_END + Y_BYTES + H_BYTES) {
    ybuf = (short*)(ws + META_END);
    h = (short*)(ws + META_END + Y_BYTES);
    usews = true;
  } else if (ws_size >= (size_t)META_END + H_BYTES) {
    h = (short*)(ws + META_END);
    ybuf = (short*)((char*)d_out + OUT_BYTES - Y_BYTES);  // tail of out; rewritten by applyK last
    usews = true;
  } else {
    ybuf = (short*)(ws + META_END);
    usews = false;
  }

  prepK<<<96, 256, 0, stream>>>(W1, W2, W3, wt, partials);
  nodeK<<<782, 256, 0, stream>>>(nodef, wt, ybuf);
  if (usews) {
    gnn2<true><<<GRID2, 512, 0, stream>>>(edgef, srcI, dstI, ybuf, b1, b2, b3,
                                          wt, partials, h, out);
  } else {
    gnn2<false><<<GRID2, 512, 0, stream>>>(edgef, srcI, dstI, ybuf, b1, b2, b3,
                                           wt, partials, h, out);
  }
  statsK<<<1, 256, 0, stream>>>(partials, gamma, beta, scsh);
  if (usews) {
    applyK<true><<<2048, 256, 0, stream>>>(h, scsh, out);
  } else {
    applyK<false><<<2048, 256, 0, stream>>>(h, scsh, out);
  }
}

// Round 8
// 193.965 us; speedup vs baseline: 1.3487x; 1.0876x over previous
//
#include <hip/hip_runtime.h>
#include <hip/hip_bf16.h>
#include <cstddef>

#define N_E 400000
#define N_V 50000
#define NEG_SLOPE 0.01f
#define BN_EPS 1e-5f
#define NT (N_E / 64)

typedef __attribute__((ext_vector_type(8))) short bf16x8;
typedef __attribute__((ext_vector_type(4))) float f32x4;

// ws layout (bytes)
#define PART_OFF   0            // 64 replicas * 256 f32 = 65536 B
#define SCALE_OFF  65536        // 256 f32 (scale[128], shift[128])
#define WT_OFF     66560        // bf16 weights, packed in MFMA A-frag chunks
// wt shorts: W1a 8192 @0 | W1b 16384 @8192 | W2 16384 @24576 | W3 16384 @40960
#define META_END   181248
#define Y_BYTES    12800000ULL  // 50000*128*2
#define H_BYTES    102400000ULL // 400000*128*2
#define OUT_BYTES  204800000ULL

__device__ __forceinline__ unsigned short f2bf(float f) {
  unsigned u = __builtin_bit_cast(unsigned, f);
  u += 0x7fffu + ((u >> 16) & 1u);            // RNE
  return (unsigned short)(u >> 16);
}
__device__ __forceinline__ float bf2f(unsigned short s) {
  return __builtin_bit_cast(float, (unsigned)s << 16);
}
__device__ __forceinline__ float lrelu(float x) {
  return x >= 0.f ? x : NEG_SLOPE * x;
}
__device__ __forceinline__ unsigned pk2(float lo, float hi) {
  return (unsigned)f2bf(lo) | ((unsigned)f2bf(hi) << 16);
}
__device__ __forceinline__ int addbf(int a, int b) {
  unsigned ua = (unsigned)a, ub = (unsigned)b;
  float l = __builtin_bit_cast(float, ua << 16) + __builtin_bit_cast(float, ub << 16);
  float h = __builtin_bit_cast(float, ua & 0xffff0000u) +
            __builtin_bit_cast(float, ub & 0xffff0000u);
  return (int)pk2(l, h);
}

// ---- one 64-edge tile per block; 256 thr / 4 waves; 2 feature-tiles per wave.
// JIT fragment loads (lifetime-bounded -> ~110 VGPR demand, no spills), LDS
// 3-buffer rotation (ef->h3, y->h2, h1) = 53.8KB -> 3 blocks/CU, 12 waves/CU.
template<bool USEWS>
__global__ __launch_bounds__(256, 3) void gnn3(
    const float* __restrict__ edgef, const int* __restrict__ srcI,
    const int* __restrict__ dstI, const short* __restrict__ ybuf,
    const float* __restrict__ b1, const float* __restrict__ b2,
    const float* __restrict__ b3, const short* __restrict__ wt,
    float* __restrict__ partials, short* __restrict__ hout,
    float* __restrict__ fout) {
  __shared__ short sA[64 * 136];   // ef (K=64, cols 0..63) -> h3
  __shared__ short sB_[64 * 136];  // ysum               -> h2
  __shared__ short sC[64 * 136];   // h1
  __shared__ float sBias[384];     // b1|b2|b3

  const int tid = threadIdx.x;
  const int lane = tid & 63;
  const int w = tid >> 6;
  const int col = lane & 15;
  const int kb = (lane >> 4) * 8;
  const int t = blockIdx.x;
  const int r4 = tid >> 2, c4 = tid & 3;

  sBias[tid] = (tid < 128) ? b1[tid] : b2[tid - 128];
  if (tid < 128) sBias[256 + tid] = b3[tid];

  // ---- stage: ef (f32->bf16) into sA, y[src]+y[dst] folded into sB_ ----
  {
    int e = t * 64 + r4;
    int si = srcI[e], di = dstI[e];
    const float4* efp = (const float4*)(edgef + (size_t)e * 64) + c4 * 4;
    float4 e0 = efp[0], e1 = efp[1], e2 = efp[2], e3 = efp[3];
    const int4* yps = (const int4*)(ybuf + (size_t)si * 128) + c4 * 4;
    const int4* ypd = (const int4*)(ybuf + (size_t)di * 128) + c4 * 4;
    int4 a0 = yps[0], a1 = yps[1], a2 = yps[2], a3 = yps[3];
    int4 d0 = ypd[0], d1 = ypd[1], d2 = ypd[2], d3 = ypd[3];
    int4 x0, x1;
    x0.x = (int)pk2(e0.x, e0.y); x0.y = (int)pk2(e0.z, e0.w);
    x0.z = (int)pk2(e1.x, e1.y); x0.w = (int)pk2(e1.z, e1.w);
    x1.x = (int)pk2(e2.x, e2.y); x1.y = (int)pk2(e2.z, e2.w);
    x1.z = (int)pk2(e3.x, e3.y); x1.w = (int)pk2(e3.z, e3.w);
    *(int4*)(sA + r4 * 136 + c4 * 16) = x0;
    *(int4*)(sA + r4 * 136 + c4 * 16 + 8) = x1;
    int4 y0, y1, y2, y3;
    y0.x = addbf(a0.x, d0.x); y0.y = addbf(a0.y, d0.y);
    y0.z = addbf(a0.z, d0.z); y0.w = addbf(a0.w, d0.w);
    y1.x = addbf(a1.x, d1.x); y1.y = addbf(a1.y, d1.y);
    y1.z = addbf(a1.z, d1.z); y1.w = addbf(a1.w, d1.w);
    y2.x = addbf(a2.x, d2.x); y2.y = addbf(a2.y, d2.y);
    y2.z = addbf(a2.z, d2.z); y2.w = addbf(a2.w, d2.w);
    y3.x = addbf(a3.x, d3.x); y3.y = addbf(a3.y, d3.y);
    y3.z = addbf(a3.z, d3.z); y3.w = addbf(a3.w, d3.w);
    short* yw = sB_ + r4 * 136 + c4 * 32;
    *(int4*)(yw) = y0; *(int4*)(yw + 8) = y1;
    *(int4*)(yw + 16) = y2; *(int4*)(yw + 24) = y3;
  }

  f32x4 acc[2][4];
  #pragma unroll
  for (int tt = 0; tt < 2; ++tt)
    #pragma unroll
    for (int et = 0; et < 4; ++et) acc[tt][et] = (f32x4){0.f, 0.f, 0.f, 0.f};
  float sE[8], sQ[8];
  #pragma unroll
  for (int i = 0; i < 8; ++i) { sE[i] = 0.f; sQ[i] = 0.f; }

  __syncthreads();                     // (1) inputs staged

  // ---- L1 (K=64): JIT frags, B from sA; epi(+y from sB_) -> sC ----
  {
    bf16x8 f1[2][2];
    #pragma unroll
    for (int tt = 0; tt < 2; ++tt)
      #pragma unroll
      for (int s = 0; s < 2; ++s)
        f1[tt][s] = *(const bf16x8*)(wt + ((((w * 2 + tt) * 2 + s) << 9) + lane * 8));
    #pragma unroll
    for (int et = 0; et < 4; ++et) {
      const short* bp = sA + (et * 16 + col) * 136 + kb;
      #pragma unroll
      for (int s = 0; s < 2; ++s) {
        bf16x8 b = *(const bf16x8*)(bp + s * 32);
        acc[0][et] = __builtin_amdgcn_mfma_f32_16x16x32_bf16(f1[0][s], b, acc[0][et], 0, 0, 0);
        acc[1][et] = __builtin_amdgcn_mfma_f32_16x16x32_bf16(f1[1][s], b, acc[1][et], 0, 0, 0);
      }
    }
    #pragma unroll
    for (int tt = 0; tt < 2; ++tt) {
      const int f = (w * 2 + tt) * 16 + (lane >> 4) * 4;
      float4 bb = *(const float4*)(sBias + f);
      #pragma unroll
      for (int et = 0; et < 4; ++et) {
        const int edge = et * 16 + col;
        short4 q = *(const short4*)(sB_ + edge * 136 + f);
        f32x4 a = acc[tt][et];
        float v0 = lrelu(a[0] + bb.x + bf2f((unsigned short)q.x));
        float v1 = lrelu(a[1] + bb.y + bf2f((unsigned short)q.y));
        float v2 = lrelu(a[2] + bb.z + bf2f((unsigned short)q.z));
        float v3 = lrelu(a[3] + bb.w + bf2f((unsigned short)q.w));
        *(int2*)(sC + edge * 136 + f) = make_int2((int)pk2(v0, v1), (int)pk2(v2, v3));
        acc[tt][et] = (f32x4){0.f, 0.f, 0.f, 0.f};
      }
    }
  }
  __syncthreads();                     // (2) h1 ready; y consumed

  // ---- L2 (K=128): B from sC; epi -> sB_ ----
  {
    bf16x8 f2[2][4];
    #pragma unroll
    for (int tt = 0; tt < 2; ++tt)
      #pragma unroll
      for (int s = 0; s < 4; ++s)
        f2[tt][s] = *(const bf16x8*)(wt + 24576 + ((((w * 2 + tt) * 4 + s) << 9) + lane * 8));
    #pragma unroll
    for (int et = 0; et < 4; ++et) {
      const short* bp = sC + (et * 16 + col) * 136 + kb;
      #pragma unroll
      for (int s = 0; s < 4; ++s) {
        bf16x8 b = *(const bf16x8*)(bp + s * 32);
        acc[0][et] = __builtin_amdgcn_mfma_f32_16x16x32_bf16(f2[0][s], b, acc[0][et], 0, 0, 0);
        acc[1][et] = __builtin_amdgcn_mfma_f32_16x16x32_bf16(f2[1][s], b, acc[1][et], 0, 0, 0);
      }
    }
    #pragma unroll
    for (int tt = 0; tt < 2; ++tt) {
      const int f = (w * 2 + tt) * 16 + (lane >> 4) * 4;
      float4 bb = *(const float4*)(sBias + 128 + f);
      #pragma unroll
      for (int et = 0; et < 4; ++et) {
        const int edge = et * 16 + col;
        f32x4 a = acc[tt][et];
        float v0 = lrelu(a[0] + bb.x), v1 = lrelu(a[1] + bb.y);
        float v2 = lrelu(a[2] + bb.z), v3 = lrelu(a[3] + bb.w);
        *(int2*)(sB_ + edge * 136 + f) = make_int2((int)pk2(v0, v1), (int)pk2(v2, v3));
        acc[tt][et] = (f32x4){0.f, 0.f, 0.f, 0.f};
      }
    }
  }
  __syncthreads();                     // (3) h2 ready

  // ---- L3 (K=128): B from sB_; epi + stats -> sA ----
  {
    bf16x8 f3[2][4];
    #pragma unroll
    for (int tt = 0; tt < 2; ++tt)
      #pragma unroll
      for (int s = 0; s < 4; ++s)
        f3[tt][s] = *(const bf16x8*)(wt + 40960 + ((((w * 2 + tt) * 4 + s) << 9) + lane * 8));
    #pragma unroll
    for (int et = 0; et < 4; ++et) {
      const short* bp = sB_ + (et * 16 + col) * 136 + kb;
      #pragma unroll
      for (int s = 0; s < 4; ++s) {
        bf16x8 b = *(const bf16x8*)(bp + s * 32);
        acc[0][et] = __builtin_amdgcn_mfma_f32_16x16x32_bf16(f3[0][s], b, acc[0][et], 0, 0, 0);
        acc[1][et] = __builtin_amdgcn_mfma_f32_16x16x32_bf16(f3[1][s], b, acc[1][et], 0, 0, 0);
      }
    }
    #pragma unroll
    for (int tt = 0; tt < 2; ++tt) {
      const int f = (w * 2 + tt) * 16 + (lane >> 4) * 4;
      float4 bb = *(const float4*)(sBias + 256 + f);
      #pragma unroll
      for (int et = 0; et < 4; ++et) {
        const int edge = et * 16 + col;
        f32x4 a = acc[tt][et];
        float v0 = lrelu(a[0] + bb.x), v1 = lrelu(a[1] + bb.y);
        float v2 = lrelu(a[2] + bb.z), v3 = lrelu(a[3] + bb.w);
        sE[tt * 4 + 0] += v0; sQ[tt * 4 + 0] += v0 * v0;
        sE[tt * 4 + 1] += v1; sQ[tt * 4 + 1] += v1 * v1;
        sE[tt * 4 + 2] += v2; sQ[tt * 4 + 2] += v2 * v2;
        sE[tt * 4 + 3] += v3; sQ[tt * 4 + 3] += v3 * v3;
        *(int2*)(sA + edge * 136 + f) = make_int2((int)pk2(v0, v1), (int)pk2(v2, v3));
      }
    }
  }
  __syncthreads();                     // (4) h3 ready in sA

  // ---- writeout h3 (coalesced) ----
  if (USEWS) {
    int4* dst = (int4*)(hout + (size_t)t * 8192);
    #pragma unroll
    for (int j = 0; j < 4; ++j)
      dst[r4 * 16 + c4 * 4 + j] = *(const int4*)(sA + r4 * 136 + c4 * 32 + j * 8);
  } else {
    float4* dst = (float4*)(fout + (size_t)t * 8192);
    #pragma unroll
    for (int j = 0; j < 4; ++j) {
      int4 tv = *(const int4*)(sA + r4 * 136 + c4 * 32 + j * 8);
      float4 o0, o1;
      o0.x = bf2f((unsigned short)((unsigned)tv.x & 0xffffu));
      o0.y = bf2f((unsigned short)((unsigned)tv.x >> 16));
      o0.z = bf2f((unsigned short)((unsigned)tv.y & 0xffffu));
      o0.w = bf2f((unsigned short)((unsigned)tv.y >> 16));
      o1.x = bf2f((unsigned short)((unsigned)tv.z & 0xffffu));
      o1.y = bf2f((unsigned short)((unsigned)tv.z >> 16));
      o1.z = bf2f((unsigned short)((unsigned)tv.w & 0xffffu));
      o1.w = bf2f((unsigned short)((unsigned)tv.w >> 16));
      dst[r4 * 32 + c4 * 8 + j * 2] = o0;
      dst[r4 * 32 + c4 * 8 + j * 2 + 1] = o1;
    }
  }

  // ---- stats: butterfly over the 16 edge-lanes, then atomics ----
  #pragma unroll
  for (int m = 1; m <= 8; m <<= 1) {
    #pragma unroll
    for (int i = 0; i < 8; ++i) {
      sE[i] += __shfl_xor(sE[i], m, 64);
      sQ[i] += __shfl_xor(sQ[i], m, 64);
    }
  }
  if (col == 0) {
    float* pp = partials + (t & 63) * 256;
    #pragma unroll
    for (int tt = 0; tt < 2; ++tt) {
      const int f = (w * 2 + tt) * 16 + (lane >> 4) * 4;
      #pragma unroll
      for (int i = 0; i < 4; ++i) {
        atomicAdd(&pp[f + i], sE[tt * 4 + i]);
        atomicAdd(&pp[128 + f + i], sQ[tt * 4 + i]);
      }
    }
  }
}

// ---- per-node precompute: y = nf * W1b  (bf16 out) ----
__global__ __launch_bounds__(256) void nodeK(const float* __restrict__ nodef,
                                             const short* __restrict__ wt,
                                             short* __restrict__ y) {
  __shared__ short sN[64 * 136];
  const int tid = threadIdx.x;
  const int lane = tid & 63;
  const int w = tid >> 6;
  const int n0 = blockIdx.x * 64;
  const int r = tid >> 2, p4 = tid & 3;
  {
    int v = n0 + r;
    int vc = v < N_V ? v : N_V - 1;
    const float4* np = (const float4*)(nodef + (size_t)vc * 128) + p4 * 8;
    #pragma unroll
    for (int j = 0; j < 8; ++j) {
      float4 a = np[j];
      *(int2*)(sN + r * 136 + p4 * 32 + j * 4) =
          make_int2((int)pk2(a.x, a.y), (int)pk2(a.z, a.w));
    }
  }
  __syncthreads();
  const short* wb = wt + 8192;
  bf16x8 fr[8];
  #pragma unroll
  for (int nt = 0; nt < 2; ++nt)
    #pragma unroll
    for (int s = 0; s < 4; ++s)
      fr[nt * 4 + s] = *(const bf16x8*)(wb + ((((w * 2 + nt) * 4 + s) << 9) + lane * 8));
  f32x4 acc[8];
  #pragma unroll
  for (int i = 0; i < 8; ++i) acc[i] = (f32x4){0.f, 0.f, 0.f, 0.f};
  const int col = lane & 15;
  const int kb = (lane >> 4) * 8;
  #pragma unroll
  for (int et = 0; et < 4; ++et) {
    const short* bp = sN + (et * 16 + col) * 136 + kb;
    #pragma unroll
    for (int s = 0; s < 4; ++s) {
      bf16x8 b = *(const bf16x8*)(bp + s * 32);
      acc[0 + et] = __builtin_amdgcn_mfma_f32_16x16x32_bf16(fr[s], b, acc[0 + et], 0, 0, 0);
      acc[4 + et] = __builtin_amdgcn_mfma_f32_16x16x32_bf16(fr[4 + s], b, acc[4 + et], 0, 0, 0);
    }
  }
  __syncthreads();   // sN input reads done
  {
    const int fb = (lane >> 4) * 4;
    #pragma unroll
    for (int nt = 0; nt < 2; ++nt) {
      const int f0 = w * 32 + nt * 16 + fb;
      #pragma unroll
      for (int et = 0; et < 4; ++et) {
        f32x4 a = acc[nt * 4 + et];
        *(int2*)(sN + (et * 16 + col) * 136 + f0) =
            make_int2((int)pk2(a[0], a[1]), (int)pk2(a[2], a[3]));
      }
    }
  }
  __syncthreads();
  if (n0 + r < N_V) {
    #pragma unroll
    for (int j = 0; j < 4; ++j) {
      int4 tv = *(const int4*)(sN + r * 136 + p4 * 32 + j * 8);
      *(int4*)(y + (size_t)(n0 + r) * 128 + p4 * 32 + j * 8) = tv;
    }
  }
}

// ---- weight pack + partials zero ----
__global__ __launch_bounds__(256) void prepK(const float* __restrict__ W1,
                                             const float* __restrict__ W2,
                                             const float* __restrict__ W3,
                                             short* __restrict__ wt,
                                             float* __restrict__ partials) {
  int b = blockIdx.x, t = threadIdx.x;
  if (b < 64) { partials[b * 256 + t] = 0.f; return; }
  int g = (b - 64) * 256 + t;
  for (int fi = g; fi < 57344; fi += 32 * 256) {
    float val;
    if (fi < 8192) {                       // W1a: 8 tiles x 2 ksteps (K=64)
      int c = fi >> 9, r = fi & 511;
      int l = r >> 3, j = r & 7;
      int tt = c >> 1, s = c & 1;
      int n = tt * 16 + (l & 15);
      int k = s * 32 + (l >> 4) * 8 + j;
      val = W1[k * 128 + n];
    } else if (fi < 24576) {               // W1b: 8 tiles x 4 ksteps (rows 64..191)
      int f2 = fi - 8192;
      int c = f2 >> 9, r = f2 & 511;
      int l = r >> 3, j = r & 7;
      int tt = c >> 2, s = c & 3;
      int n = tt * 16 + (l & 15);
      int k = s * 32 + (l >> 4) * 8 + j;
      val = W1[(64 + k) * 128 + n];
    } else if (fi < 40960) {               // W2
      int f2 = fi - 24576;
      int c = f2 >> 9, r = f2 & 511;
      int l = r >> 3, j = r & 7;
      int tt = c >> 2, s = c & 3;
      int n = tt * 16 + (l & 15);
      int k = s * 32 + (l >> 4) * 8 + j;
      val = W2[k * 128 + n];
    } else {                               // W3
      int f3 = fi - 40960;
      int c = f3 >> 9, r = f3 & 511;
      int l = r >> 3, j = r & 7;
      int tt = c >> 2, s = c & 3;
      int n = tt * 16 + (l & 15);
      int k = s * 32 + (l >> 4) * 8 + j;
      val = W3[k * 128 + n];
    }
    wt[fi] = (short)f2bf(val);
  }
}

__global__ __launch_bounds__(256) void statsK(const float* __restrict__ partials,
                                              const float* __restrict__ gamma,
                                              const float* __restrict__ beta,
                                              float* __restrict__ scsh) {
  __shared__ float tmp[256];
  int t = threadIdx.x;
  float a = 0.f;
  #pragma unroll 8
  for (int r = 0; r < 64; ++r) a += partials[r * 256 + t];
  tmp[t] = a;
  __syncthreads();
  if (t < 128) {
    float S = tmp[t], S2 = tmp[t + 128];
    float mean = S / (float)N_E;
    float var = S2 / (float)N_E - mean * mean;   // biased, matches reference
    float inv = rsqrtf(var + BN_EPS);
    float sc = gamma[t] * inv;
    scsh[t] = sc;
    scsh[t + 128] = beta[t] - mean * sc;
  }
}

template<bool USEWS>
__global__ __launch_bounds__(256) void applyK(const short* __restrict__ h,
                                              const float* __restrict__ scsh,
                                              float* out) {
  const int TOT4 = N_E * 128 / 4;
  int j0 = blockIdx.x * 256 + threadIdx.x;
  int c4 = j0 & 31;
  float4 sc = *(const float4*)(scsh + c4 * 4);
  float4 sh = *(const float4*)(scsh + 128 + c4 * 4);
  int stride = gridDim.x * 256;
  for (int j = j0; j < TOT4; j += stride) {
    float4 v;
    if (USEWS) {
      short4 s = *(const short4*)(h + (size_t)j * 4);
      v.x = bf2f((unsigned short)s.x) * sc.x + sh.x;
      v.y = bf2f((unsigned short)s.y) * sc.y + sh.y;
      v.z = bf2f((unsigned short)s.z) * sc.z + sh.z;
      v.w = bf2f((unsigned short)s.w) * sc.w + sh.w;
    } else {
      float4 hv = ((const float4*)out)[j];
      v.x = hv.x * sc.x + sh.x;
      v.y = hv.y * sc.y + sh.y;
      v.z = hv.z * sc.z + sh.z;
      v.w = hv.w * sc.w + sh.w;
    }
    ((float4*)out)[j] = v;
  }
}

extern "C" void kernel_launch(void* const* d_in, const int* in_sizes, int n_in,
                              void* d_out, int out_size, void* d_ws, size_t ws_size,
                              hipStream_t stream) {
  const float* nodef = (const float*)d_in[0];
  const float* edgef = (const float*)d_in[1];
  const int* srcI = (const int*)d_in[2];
  const int* dstI = (const int*)d_in[3];
  const float* W1 = (const float*)d_in[4];
  const float* b1 = (const float*)d_in[5];
  const float* W2 = (const float*)d_in[6];
  const float* b2 = (const float*)d_in[7];
  const float* W3 = (const float*)d_in[8];
  const float* b3 = (const float*)d_in[9];
  const float* gamma = (const float*)d_in[10];
  const float* beta = (const float*)d_in[11];
  float* out = (float*)d_out;
  char* ws = (char*)d_ws;

  float* partials = (float*)(ws + PART_OFF);
  float* scsh = (float*)(ws + SCALE_OFF);
  short* wt = (short*)(ws + WT_OFF);
  short* ybuf;
  short* h = nullptr;
  bool usews;
  if (ws_size >= (size_t)META_END + Y_BYTES + H_BYTES) {
    ybuf = (short*)(ws + META_END);
    h = (short*)(ws + META_END + Y_BYTES);
    usews = true;
  } else if (ws_size >= (size_t)META_END + H_BYTES) {
    h = (short*)(ws + META_END);
    ybuf = (short*)((char*)d_out + OUT_BYTES - Y_BYTES);  // tail of out; rewritten by applyK last
    usews = true;
  } else {
    ybuf = (short*)(ws + META_END);
    usews = false;
  }

  prepK<<<96, 256, 0, stream>>>(W1, W2, W3, wt, partials);
  nodeK<<<782, 256, 0, stream>>>(nodef, wt, ybuf);
  if (usews) {
    gnn3<true><<<NT, 256, 0, stream>>>(edgef, srcI, dstI, ybuf, b1, b2, b3,
                                       wt, partials, h, out);
  } else {
    gnn3<false><<<NT, 256, 0, stream>>>(edgef, srcI, dstI, ybuf, b1, b2, b3,
                                        wt, partials, h, out);
  }
  statsK<<<1, 256, 0, stream>>>(partials, gamma, beta, scsh);
  if (usews) {
    applyK<true><<<2048, 256, 0, stream>>>(h, scsh, out);
  } else {
    applyK<false><<<2048, 256, 0, stream>>>(h, scsh, out);
  }
}

// Round 9
// 184.317 us; speedup vs baseline: 1.4193x; 1.0523x over previous
//
#include <hip/hip_runtime.h>
#include <hip/hip_bf16.h>
#include <cstddef>

#define N_E 400000
#define N_V 50000
#define NEG_SLOPE 0.01f
#define BN_EPS 1e-5f
#define NT (N_E / 64)

typedef __attribute__((ext_vector_type(8))) short bf16x8;
typedef __attribute__((ext_vector_type(4))) float f32x4;

// ws layout (bytes)
#define PART_OFF   0            // 64 replicas * 256 f32 = 65536 B
#define SCALE_OFF  65536        // 256 f32 (scale[128], shift[128])
#define WT_OFF     66560        // bf16 weights, packed in MFMA A-frag chunks
// wt shorts: W1a 8192 @0 | W1b 16384 @8192 | W2 16384 @24576 | W3 16384 @40960
#define META_END   181248
#define Y_BYTES    12800000ULL  // 50000*128*2
#define H_BYTES    102400000ULL // 400000*128*2
#define OUT_BYTES  204800000ULL

// XOR-swizzled LDS addressing (8-short chunks; spreads banks, no padding)
#define SWX(row, chunk) ((row) * 64 + ((((chunk) ^ ((row) & 7))) << 3))
#define SWM(row, chunk) ((row) * 128 + ((((chunk) ^ ((row) & 7))) << 3))

__device__ __forceinline__ unsigned short f2bf(float f) {
  unsigned u = __builtin_bit_cast(unsigned, f);
  u += 0x7fffu + ((u >> 16) & 1u);            // RNE
  return (unsigned short)(u >> 16);
}
__device__ __forceinline__ float bf2f(unsigned short s) {
  return __builtin_bit_cast(float, (unsigned)s << 16);
}
__device__ __forceinline__ float lrelu(float x) {
  return x >= 0.f ? x : NEG_SLOPE * x;
}
// pack 2 f32 -> 2 bf16 via HW cvt (T12): 1 inst vs ~10 integer-emulated
__device__ __forceinline__ unsigned pk2(float lo, float hi) {
  unsigned r;
  asm("v_cvt_pk_bf16_f32 %0, %1, %2" : "=v"(r) : "v"(lo), "v"(hi));
  return r;
}
__device__ __forceinline__ int addbf(int a, int b) {
  unsigned ua = (unsigned)a, ub = (unsigned)b;
  float l = __builtin_bit_cast(float, ua << 16) + __builtin_bit_cast(float, ub << 16);
  float h = __builtin_bit_cast(float, ua & 0xffff0000u) +
            __builtin_bit_cast(float, ub & 0xffff0000u);
  return (int)pk2(l, h);
}

// ---- one 64-edge tile per block; 256 thr / 4 waves; 2 feature-tiles/wave.
// LDS: sX(ef 8KB) + sM(y->h2 16KB) + sN(h1->h3 16KB) = 40960 B exactly ->
// 4 blocks/CU (16 waves). JIT frags + JIT bias -> ~85 VGPR demand.
template<bool USEWS>
__global__ __launch_bounds__(256, 4) void gnn4(
    const float* __restrict__ edgef, const int* __restrict__ srcI,
    const int* __restrict__ dstI, const short* __restrict__ ybuf,
    const float* __restrict__ b1, const float* __restrict__ b2,
    const float* __restrict__ b3, const short* __restrict__ wt,
    float* __restrict__ partials, short* __restrict__ hout,
    float* __restrict__ fout) {
  __shared__ short sX[64 * 64];    // ef tile (K=64), swizzled
  __shared__ short sM[64 * 128];   // ysum -> h2, swizzled
  __shared__ short sN[64 * 128];   // h1 -> h3, swizzled

  const int tid = threadIdx.x;
  const int lane = tid & 63;
  const int w = tid >> 6;
  const int col = lane & 15;
  const int lq = lane >> 4;        // 0..3
  const int t = blockIdx.x;
  const int r4 = tid >> 2, c4 = tid & 3;

  // ---- stage: ef (f32->bf16) into sX, y[src]+y[dst] folded into sM ----
  {
    int e = t * 64 + r4;
    int si = srcI[e], di = dstI[e];
    const float4* efp = (const float4*)(edgef + (size_t)e * 64) + c4 * 4;
    float4 e0 = efp[0], e1 = efp[1], e2 = efp[2], e3 = efp[3];
    const int4* yps = (const int4*)(ybuf + (size_t)si * 128) + c4 * 4;
    const int4* ypd = (const int4*)(ybuf + (size_t)di * 128) + c4 * 4;
    int4 a0 = yps[0], a1 = yps[1], a2 = yps[2], a3 = yps[3];
    int4 d0 = ypd[0], d1 = ypd[1], d2 = ypd[2], d3 = ypd[3];
    int4 x0, x1;
    x0.x = (int)pk2(e0.x, e0.y); x0.y = (int)pk2(e0.z, e0.w);
    x0.z = (int)pk2(e1.x, e1.y); x0.w = (int)pk2(e1.z, e1.w);
    x1.x = (int)pk2(e2.x, e2.y); x1.y = (int)pk2(e2.z, e2.w);
    x1.z = (int)pk2(e3.x, e3.y); x1.w = (int)pk2(e3.z, e3.w);
    *(int4*)(sX + SWX(r4, c4 * 2)) = x0;
    *(int4*)(sX + SWX(r4, c4 * 2 + 1)) = x1;
    int4 y0, y1, y2, y3;
    y0.x = addbf(a0.x, d0.x); y0.y = addbf(a0.y, d0.y);
    y0.z = addbf(a0.z, d0.z); y0.w = addbf(a0.w, d0.w);
    y1.x = addbf(a1.x, d1.x); y1.y = addbf(a1.y, d1.y);
    y1.z = addbf(a1.z, d1.z); y1.w = addbf(a1.w, d1.w);
    y2.x = addbf(a2.x, d2.x); y2.y = addbf(a2.y, d2.y);
    y2.z = addbf(a2.z, d2.z); y2.w = addbf(a2.w, d2.w);
    y3.x = addbf(a3.x, d3.x); y3.y = addbf(a3.y, d3.y);
    y3.z = addbf(a3.z, d3.z); y3.w = addbf(a3.w, d3.w);
    *(int4*)(sM + SWM(r4, c4 * 4 + 0)) = y0;
    *(int4*)(sM + SWM(r4, c4 * 4 + 1)) = y1;
    *(int4*)(sM + SWM(r4, c4 * 4 + 2)) = y2;
    *(int4*)(sM + SWM(r4, c4 * 4 + 3)) = y3;
  }

  f32x4 acc[2][4];
  #pragma unroll
  for (int tt = 0; tt < 2; ++tt)
    #pragma unroll
    for (int et = 0; et < 4; ++et) acc[tt][et] = (f32x4){0.f, 0.f, 0.f, 0.f};
  float sE[8], sQ[8];
  #pragma unroll
  for (int i = 0; i < 8; ++i) { sE[i] = 0.f; sQ[i] = 0.f; }

  __syncthreads();                     // (1) inputs staged

  // ---- L1 (K=64): B from sX; epi(+y from sM) -> sN ----
  {
    bf16x8 f1[2][2];
    #pragma unroll
    for (int tt = 0; tt < 2; ++tt)
      #pragma unroll
      for (int s = 0; s < 2; ++s)
        f1[tt][s] = *(const bf16x8*)(wt + ((((w * 2 + tt) * 2 + s) << 9) + lane * 8));
    float4 bbA = *(const float4*)(b1 + (w * 2 + 0) * 16 + lq * 4);
    float4 bbB = *(const float4*)(b1 + (w * 2 + 1) * 16 + lq * 4);
    #pragma unroll
    for (int et = 0; et < 4; ++et) {
      const int row = et * 16 + col;
      #pragma unroll
      for (int s = 0; s < 2; ++s) {
        bf16x8 b = *(const bf16x8*)(sX + SWX(row, lq + s * 4));
        acc[0][et] = __builtin_amdgcn_mfma_f32_16x16x32_bf16(f1[0][s], b, acc[0][et], 0, 0, 0);
        acc[1][et] = __builtin_amdgcn_mfma_f32_16x16x32_bf16(f1[1][s], b, acc[1][et], 0, 0, 0);
      }
    }
    #pragma unroll
    for (int tt = 0; tt < 2; ++tt) {
      const int f0 = (w * 2 + tt) * 16 + lq * 4;
      const int ch = f0 >> 3, sub = f0 & 7;
      float4 bb = tt ? bbB : bbA;
      #pragma unroll
      for (int et = 0; et < 4; ++et) {
        const int edge = et * 16 + col;
        short4 q = *(const short4*)(sM + SWM(edge, ch) + sub);
        f32x4 a = acc[tt][et];
        float v0 = lrelu(a[0] + bb.x + bf2f((unsigned short)q.x));
        float v1 = lrelu(a[1] + bb.y + bf2f((unsigned short)q.y));
        float v2 = lrelu(a[2] + bb.z + bf2f((unsigned short)q.z));
        float v3 = lrelu(a[3] + bb.w + bf2f((unsigned short)q.w));
        *(int2*)(sN + SWM(edge, ch) + sub) = make_int2((int)pk2(v0, v1), (int)pk2(v2, v3));
        acc[tt][et] = (f32x4){0.f, 0.f, 0.f, 0.f};
      }
    }
  }
  __syncthreads();                     // (2) h1 in sN; y consumed

  // ---- L2 (K=128): B from sN; epi -> sM ----
  {
    bf16x8 f2[2][4];
    #pragma unroll
    for (int tt = 0; tt < 2; ++tt)
      #pragma unroll
      for (int s = 0; s < 4; ++s)
        f2[tt][s] = *(const bf16x8*)(wt + 24576 + ((((w * 2 + tt) * 4 + s) << 9) + lane * 8));
    float4 bbA = *(const float4*)(b2 + (w * 2 + 0) * 16 + lq * 4);
    float4 bbB = *(const float4*)(b2 + (w * 2 + 1) * 16 + lq * 4);
    #pragma unroll
    for (int et = 0; et < 4; ++et) {
      const int row = et * 16 + col;
      #pragma unroll
      for (int s = 0; s < 4; ++s) {
        bf16x8 b = *(const bf16x8*)(sN + SWM(row, lq + s * 4));
        acc[0][et] = __builtin_amdgcn_mfma_f32_16x16x32_bf16(f2[0][s], b, acc[0][et], 0, 0, 0);
        acc[1][et] = __builtin_amdgcn_mfma_f32_16x16x32_bf16(f2[1][s], b, acc[1][et], 0, 0, 0);
      }
    }
    #pragma unroll
    for (int tt = 0; tt < 2; ++tt) {
      const int f0 = (w * 2 + tt) * 16 + lq * 4;
      const int ch = f0 >> 3, sub = f0 & 7;
      float4 bb = tt ? bbB : bbA;
      #pragma unroll
      for (int et = 0; et < 4; ++et) {
        const int edge = et * 16 + col;
        f32x4 a = acc[tt][et];
        float v0 = lrelu(a[0] + bb.x), v1 = lrelu(a[1] + bb.y);
        float v2 = lrelu(a[2] + bb.z), v3 = lrelu(a[3] + bb.w);
        *(int2*)(sM + SWM(edge, ch) + sub) = make_int2((int)pk2(v0, v1), (int)pk2(v2, v3));
        acc[tt][et] = (f32x4){0.f, 0.f, 0.f, 0.f};
      }
    }
  }
  __syncthreads();                     // (3) h2 in sM

  // ---- L3 (K=128): B from sM; epi + stats -> sN ----
  {
    bf16x8 f3[2][4];
    #pragma unroll
    for (int tt = 0; tt < 2; ++tt)
      #pragma unroll
      for (int s = 0; s < 4; ++s)
        f3[tt][s] = *(const bf16x8*)(wt + 40960 + ((((w * 2 + tt) * 4 + s) << 9) + lane * 8));
    float4 bbA = *(const float4*)(b3 + (w * 2 + 0) * 16 + lq * 4);
    float4 bbB = *(const float4*)(b3 + (w * 2 + 1) * 16 + lq * 4);
    #pragma unroll
    for (int et = 0; et < 4; ++et) {
      const int row = et * 16 + col;
      #pragma unroll
      for (int s = 0; s < 4; ++s) {
        bf16x8 b = *(const bf16x8*)(sM + SWM(row, lq + s * 4));
        acc[0][et] = __builtin_amdgcn_mfma_f32_16x16x32_bf16(f3[0][s], b, acc[0][et], 0, 0, 0);
        acc[1][et] = __builtin_amdgcn_mfma_f32_16x16x32_bf16(f3[1][s], b, acc[1][et], 0, 0, 0);
      }
    }
    #pragma unroll
    for (int tt = 0; tt < 2; ++tt) {
      const int f0 = (w * 2 + tt) * 16 + lq * 4;
      const int ch = f0 >> 3, sub = f0 & 7;
      float4 bb = tt ? bbB : bbA;
      #pragma unroll
      for (int et = 0; et < 4; ++et) {
        const int edge = et * 16 + col;
        f32x4 a = acc[tt][et];
        float v0 = lrelu(a[0] + bb.x), v1 = lrelu(a[1] + bb.y);
        float v2 = lrelu(a[2] + bb.z), v3 = lrelu(a[3] + bb.w);
        sE[tt * 4 + 0] += v0; sQ[tt * 4 + 0] += v0 * v0;
        sE[tt * 4 + 1] += v1; sQ[tt * 4 + 1] += v1 * v1;
        sE[tt * 4 + 2] += v2; sQ[tt * 4 + 2] += v2 * v2;
        sE[tt * 4 + 3] += v3; sQ[tt * 4 + 3] += v3 * v3;
        *(int2*)(sN + SWM(edge, ch) + sub) = make_int2((int)pk2(v0, v1), (int)pk2(v2, v3));
      }
    }
  }
  __syncthreads();                     // (4) h3 in sN

  // ---- writeout h3 (coalesced) ----
  if (USEWS) {
    int4* dst = (int4*)(hout + (size_t)t * 8192);
    #pragma unroll
    for (int j = 0; j < 4; ++j)
      dst[r4 * 16 + c4 * 4 + j] = *(const int4*)(sN + SWM(r4, c4 * 4 + j));
  } else {
    float4* dst = (float4*)(fout + (size_t)t * 8192);
    #pragma unroll
    for (int j = 0; j < 4; ++j) {
      int4 tv = *(const int4*)(sN + SWM(r4, c4 * 4 + j));
      float4 o0, o1;
      o0.x = bf2f((unsigned short)((unsigned)tv.x & 0xffffu));
      o0.y = bf2f((unsigned short)((unsigned)tv.x >> 16));
      o0.z = bf2f((unsigned short)((unsigned)tv.y & 0xffffu));
      o0.w = bf2f((unsigned short)((unsigned)tv.y >> 16));
      o1.x = bf2f((unsigned short)((unsigned)tv.z & 0xffffu));
      o1.y = bf2f((unsigned short)((unsigned)tv.z >> 16));
      o1.z = bf2f((unsigned short)((unsigned)tv.w & 0xffffu));
      o1.w = bf2f((unsigned short)((unsigned)tv.w >> 16));
      dst[r4 * 32 + c4 * 8 + j * 2] = o0;
      dst[r4 * 32 + c4 * 8 + j * 2 + 1] = o1;
    }
  }

  // ---- stats: butterfly over the 16 edge-lanes, then atomics ----
  #pragma unroll
  for (int m = 1; m <= 8; m <<= 1) {
    #pragma unroll
    for (int i = 0; i < 8; ++i) {
      sE[i] += __shfl_xor(sE[i], m, 64);
      sQ[i] += __shfl_xor(sQ[i], m, 64);
    }
  }
  if (col == 0) {
    float* pp = partials + (t & 63) * 256;
    #pragma unroll
    for (int tt = 0; tt < 2; ++tt) {
      const int f0 = (w * 2 + tt) * 16 + lq * 4;
      #pragma unroll
      for (int i = 0; i < 4; ++i) {
        atomicAdd(&pp[f0 + i], sE[tt * 4 + i]);
        atomicAdd(&pp[128 + f0 + i], sQ[tt * 4 + i]);
      }
    }
  }
}

// ---- per-node precompute: y = nf * W1b  (bf16 out) ----
__global__ __launch_bounds__(256) void nodeK(const float* __restrict__ nodef,
                                             const short* __restrict__ wt,
                                             short* __restrict__ y) {
  __shared__ short sN[64 * 136];
  const int tid = threadIdx.x;
  const int lane = tid & 63;
  const int w = tid >> 6;
  const int n0 = blockIdx.x * 64;
  const int r = tid >> 2, p4 = tid & 3;
  {
    int v = n0 + r;
    int vc = v < N_V ? v : N_V - 1;
    const float4* np = (const float4*)(nodef + (size_t)vc * 128) + p4 * 8;
    #pragma unroll
    for (int j = 0; j < 8; ++j) {
      float4 a = np[j];
      *(int2*)(sN + r * 136 + p4 * 32 + j * 4) =
          make_int2((int)pk2(a.x, a.y), (int)pk2(a.z, a.w));
    }
  }
  __syncthreads();
  const short* wb = wt + 8192;
  bf16x8 fr[8];
  #pragma unroll
  for (int nt = 0; nt < 2; ++nt)
    #pragma unroll
    for (int s = 0; s < 4; ++s)
      fr[nt * 4 + s] = *(const bf16x8*)(wb + ((((w * 2 + nt) * 4 + s) << 9) + lane * 8));
  f32x4 acc[8];
  #pragma unroll
  for (int i = 0; i < 8; ++i) acc[i] = (f32x4){0.f, 0.f, 0.f, 0.f};
  const int col = lane & 15;
  const int kb = (lane >> 4) * 8;
  #pragma unroll
  for (int et = 0; et < 4; ++et) {
    const short* bp = sN + (et * 16 + col) * 136 + kb;
    #pragma unroll
    for (int s = 0; s < 4; ++s) {
      bf16x8 b = *(const bf16x8*)(bp + s * 32);
      acc[0 + et] = __builtin_amdgcn_mfma_f32_16x16x32_bf16(fr[s], b, acc[0 + et], 0, 0, 0);
      acc[4 + et] = __builtin_amdgcn_mfma_f32_16x16x32_bf16(fr[4 + s], b, acc[4 + et], 0, 0, 0);
    }
  }
  __syncthreads();   // sN input reads done
  {
    const int fb = (lane >> 4) * 4;
    #pragma unroll
    for (int nt = 0; nt < 2; ++nt) {
      const int f0 = w * 32 + nt * 16 + fb;
      #pragma unroll
      for (int et = 0; et < 4; ++et) {
        f32x4 a = acc[nt * 4 + et];
        *(int2*)(sN + (et * 16 + col) * 136 + f0) =
            make_int2((int)pk2(a[0], a[1]), (int)pk2(a[2], a[3]));
      }
    }
  }
  __syncthreads();
  if (n0 + r < N_V) {
    #pragma unroll
    for (int j = 0; j < 4; ++j) {
      int4 tv = *(const int4*)(sN + r * 136 + p4 * 32 + j * 8);
      *(int4*)(y + (size_t)(n0 + r) * 128 + p4 * 32 + j * 8) = tv;
    }
  }
}

// ---- weight pack + partials zero ----
__global__ __launch_bounds__(256) void prepK(const float* __restrict__ W1,
                                             const float* __restrict__ W2,
                                             const float* __restrict__ W3,
                                             short* __restrict__ wt,
                                             float* __restrict__ partials) {
  int b = blockIdx.x, t = threadIdx.x;
  if (b < 64) { partials[b * 256 + t] = 0.f; return; }
  int g = (b - 64) * 256 + t;
  for (int fi = g; fi < 57344; fi += 32 * 256) {
    float val;
    if (fi < 8192) {                       // W1a: 8 tiles x 2 ksteps (K=64)
      int c = fi >> 9, r = fi & 511;
      int l = r >> 3, j = r & 7;
      int tt = c >> 1, s = c & 1;
      int n = tt * 16 + (l & 15);
      int k = s * 32 + (l >> 4) * 8 + j;
      val = W1[k * 128 + n];
    } else if (fi < 24576) {               // W1b: 8 tiles x 4 ksteps (rows 64..191)
      int f2 = fi - 8192;
      int c = f2 >> 9, r = f2 & 511;
      int l = r >> 3, j = r & 7;
      int tt = c >> 2, s = c & 3;
      int n = tt * 16 + (l & 15);
      int k = s * 32 + (l >> 4) * 8 + j;
      val = W1[(64 + k) * 128 + n];
    } else if (fi < 40960) {               // W2
      int f2 = fi - 24576;
      int c = f2 >> 9, r = f2 & 511;
      int l = r >> 3, j = r & 7;
      int tt = c >> 2, s = c & 3;
      int n = tt * 16 + (l & 15);
      int k = s * 32 + (l >> 4) * 8 + j;
      val = W2[k * 128 + n];
    } else {                               // W3
      int f3 = fi - 40960;
      int c = f3 >> 9, r = f3 & 511;
      int l = r >> 3, j = r & 7;
      int tt = c >> 2, s = c & 3;
      int n = tt * 16 + (l & 15);
      int k = s * 32 + (l >> 4) * 8 + j;
      val = W3[k * 128 + n];
    }
    wt[fi] = (short)f2bf(val);
  }
}

__global__ __launch_bounds__(256) void statsK(const float* __restrict__ partials,
                                              const float* __restrict__ gamma,
                                              const float* __restrict__ beta,
                                              float* __restrict__ scsh) {
  __shared__ float tmp[256];
  int t = threadIdx.x;
  float a = 0.f;
  #pragma unroll 8
  for (int r = 0; r < 64; ++r) a += partials[r * 256 + t];
  tmp[t] = a;
  __syncthreads();
  if (t < 128) {
    float S = tmp[t], S2 = tmp[t + 128];
    float mean = S / (float)N_E;
    float var = S2 / (float)N_E - mean * mean;   // biased, matches reference
    float inv = rsqrtf(var + BN_EPS);
    float sc = gamma[t] * inv;
    scsh[t] = sc;
    scsh[t + 128] = beta[t] - mean * sc;
  }
}

template<bool USEWS>
__global__ __launch_bounds__(256) void applyK(const short* __restrict__ h,
                                              const float* __restrict__ scsh,
                                              float* out) {
  const int TOT4 = N_E * 128 / 4;
  int j0 = blockIdx.x * 256 + threadIdx.x;
  int c4 = j0 & 31;
  float4 sc = *(const float4*)(scsh + c4 * 4);
  float4 sh = *(const float4*)(scsh + 128 + c4 * 4);
  int stride = gridDim.x * 256;
  for (int j = j0; j < TOT4; j += stride) {
    float4 v;
    if (USEWS) {
      short4 s = *(const short4*)(h + (size_t)j * 4);
      v.x = bf2f((unsigned short)s.x) * sc.x + sh.x;
      v.y = bf2f((unsigned short)s.y) * sc.y + sh.y;
      v.z = bf2f((unsigned short)s.z) * sc.z + sh.z;
      v.w = bf2f((unsigned short)s.w) * sc.w + sh.w;
    } else {
      float4 hv = ((const float4*)out)[j];
      v.x = hv.x * sc.x + sh.x;
      v.y = hv.y * sc.y + sh.y;
      v.z = hv.z * sc.z + sh.z;
      v.w = hv.w * sc.w + sh.w;
    }
    ((float4*)out)[j] = v;
  }
}

extern "C" void kernel_launch(void* const* d_in, const int* in_sizes, int n_in,
                              void* d_out, int out_size, void* d_ws, size_t ws_size,
                              hipStream_t stream) {
  const float* nodef = (const float*)d_in[0];
  const float* edgef = (const float*)d_in[1];
  const int* srcI = (const int*)d_in[2];
  const int* dstI = (const int*)d_in[3];
  const float* W1 = (const float*)d_in[4];
  const float* b1 = (const float*)d_in[5];
  const float* W2 = (const float*)d_in[6];
  const float* b2 = (const float*)d_in[7];
  const float* W3 = (const float*)d_in[8];
  const float* b3 = (const float*)d_in[9];
  const float* gamma = (const float*)d_in[10];
  const float* beta = (const float*)d_in[11];
  float* out = (float*)d_out;
  char* ws = (char*)d_ws;

  float* partials = (float*)(ws + PART_OFF);
  float* scsh = (float*)(ws + SCALE_OFF);
  short* wt = (short*)(ws + WT_OFF);
  short* ybuf;
  short* h = nullptr;
  bool usews;
  if (ws_size >= (size_t)META_END + Y_BYTES + H_BYTES) {
    ybuf = (short*)(ws + META_END);
    h = (short*)(ws + META_END + Y_BYTES);
    usews = true;
  } else if (ws_size >= (size_t)META_END + H_BYTES) {
    h = (short*)(ws + META_END);
    ybuf = (short*)((char*)d_out + OUT_BYTES - Y_BYTES);  // tail of out; rewritten by applyK last
    usews = true;
  } else {
    ybuf = (short*)(ws + META_END);
    usews = false;
  }

  prepK<<<96, 256, 0, stream>>>(W1, W2, W3, wt, partials);
  nodeK<<<782, 256, 0, stream>>>(nodef, wt, ybuf);
  if (usews) {
    gnn4<true><<<NT, 256, 0, stream>>>(edgef, srcI, dstI, ybuf, b1, b2, b3,
                                       wt, partials, h, out);
  } else {
    gnn4<false><<<NT, 256, 0, stream>>>(edgef, srcI, dstI, ybuf, b1, b2, b3,
                                        wt, partials, h, out);
  }
  statsK<<<1, 256, 0, stream>>>(partials, gamma, beta, scsh);
  if (usews) {
    applyK<true><<<2048, 256, 0, stream>>>(h, scsh, out);
  } else {
    applyK<false><<<2048, 256, 0, stream>>>(h, scsh, out);
  }
}

// Round 10
// 182.287 us; speedup vs baseline: 1.4351x; 1.0111x over previous
//
#include <hip/hip_runtime.h>
#include <hip/hip_bf16.h>
#include <cstddef>

#define N_E 400000
#define N_V 50000
#define NEG_SLOPE 0.01f
#define BN_EPS 1e-5f
#define NT (N_E / 64)

typedef __attribute__((ext_vector_type(8))) short bf16x8;
typedef __attribute__((ext_vector_type(4))) float f32x4;

// ws layout (bytes)
#define PART_OFF   0            // 64 replicas * 256 f32 = 65536 B
#define SCALE_OFF  65536        // 256 f32 (scale[128], shift[128])
#define WT_OFF     66560        // bf16 weights, packed in MFMA A-frag chunks
// wt shorts: W1a 8192 @0 | W1b 16384 @8192 | W2 16384 @24576 | W3 16384 @40960
#define META_END   181248
#define Y_BYTES    12800000ULL  // 50000*128*2
#define H_BYTES    102400000ULL // 400000*128*2
#define OUT_BYTES  204800000ULL

// XOR-swizzled LDS addressing (8-short chunks)
#define SWX(row, chunk) ((row) * 64 + ((((chunk) ^ ((row) & 7))) << 3))
#define SWM(row, chunk) ((row) * 128 + ((((chunk) ^ ((row) & 7))) << 3))

__device__ __forceinline__ unsigned short f2bf(float f) {
  unsigned u = __builtin_bit_cast(unsigned, f);
  u += 0x7fffu + ((u >> 16) & 1u);            // RNE
  return (unsigned short)(u >> 16);
}
__device__ __forceinline__ float bf2f(unsigned short s) {
  return __builtin_bit_cast(float, (unsigned)s << 16);
}
__device__ __forceinline__ float lrelu(float x) {
  return x >= 0.f ? x : NEG_SLOPE * x;
}
// pack 2 f32 -> 2 bf16 via HW cvt
__device__ __forceinline__ unsigned pk2(float lo, float hi) {
  unsigned r;
  asm("v_cvt_pk_bf16_f32 %0, %1, %2" : "=v"(r) : "v"(lo), "v"(hi));
  return r;
}
__device__ __forceinline__ int addbf(int a, int b) {
  unsigned ua = (unsigned)a, ub = (unsigned)b;
  float l = __builtin_bit_cast(float, ua << 16) + __builtin_bit_cast(float, ub << 16);
  float h = __builtin_bit_cast(float, ua & 0xffff0000u) +
            __builtin_bit_cast(float, ub & 0xffff0000u);
  return (int)pk2(l, h);
}

// ---- process one 64-edge tile (3 phases); PF = prefetch tile tn into regs
// and drop it into LDS as buffers free up. Buffers: sX=ef, sY=y(->h2), sZ=h1.
template<bool USEWS, bool PF>
__device__ __forceinline__ void doTile(
    int t, int tn,
    const float* __restrict__ edgef, const int* __restrict__ srcI,
    const int* __restrict__ dstI, const short* __restrict__ ybuf,
    const float* __restrict__ b1, const float* __restrict__ b2,
    const float* __restrict__ b3, const short* __restrict__ wt,
    short* __restrict__ hout, float* __restrict__ fout,
    short* sX, short* sY, short* sZ,
    f32x4 (&acc)[2][4], float (&sE)[8], float (&sQv)[8],
    int lane, int w, int col, int lq, int r4, int c4) {
  int4 xa, xb;                        // next-tile ef (bf16-packed)
  int4 a0, a1, a2, a3, d0, d1, d2, d3;
  // ---------- Phase 1: L1 (K=64) ; PF: issue next-tile loads ----------
  if (PF) {
    int e = tn * 64 + r4;
    int si = srcI[e], di = dstI[e];
    const float4* efp = (const float4*)(edgef + (size_t)e * 64) + c4 * 4;
    float4 e0 = efp[0], e1 = efp[1], e2 = efp[2], e3 = efp[3];
    xa.x = (int)pk2(e0.x, e0.y); xa.y = (int)pk2(e0.z, e0.w);
    xa.z = (int)pk2(e1.x, e1.y); xa.w = (int)pk2(e1.z, e1.w);
    xb.x = (int)pk2(e2.x, e2.y); xb.y = (int)pk2(e2.z, e2.w);
    xb.z = (int)pk2(e3.x, e3.y); xb.w = (int)pk2(e3.z, e3.w);
    const int4* yps = (const int4*)(ybuf + (size_t)si * 128) + c4 * 4;
    const int4* ypd = (const int4*)(ybuf + (size_t)di * 128) + c4 * 4;
    a0 = yps[0]; a1 = yps[1]; a2 = yps[2]; a3 = yps[3];
    d0 = ypd[0]; d1 = ypd[1]; d2 = ypd[2]; d3 = ypd[3];
  }
  {
    bf16x8 f1[2][2];
    #pragma unroll
    for (int tt = 0; tt < 2; ++tt)
      #pragma unroll
      for (int s = 0; s < 2; ++s)
        f1[tt][s] = *(const bf16x8*)(wt + ((((w * 2 + tt) * 2 + s) << 9) + lane * 8));
    #pragma unroll
    for (int et = 0; et < 4; ++et) {
      const int row = et * 16 + col;
      #pragma unroll
      for (int s = 0; s < 2; ++s) {
        bf16x8 b = *(const bf16x8*)(sX + SWX(row, lq + s * 4));
        acc[0][et] = __builtin_amdgcn_mfma_f32_16x16x32_bf16(f1[0][s], b, acc[0][et], 0, 0, 0);
        acc[1][et] = __builtin_amdgcn_mfma_f32_16x16x32_bf16(f1[1][s], b, acc[1][et], 0, 0, 0);
      }
    }
    #pragma unroll
    for (int tt = 0; tt < 2; ++tt) {
      const int f0 = (w * 2 + tt) * 16 + lq * 4;
      const int ch = f0 >> 3, sub = f0 & 7;
      float4 bb = *(const float4*)(b1 + f0);
      #pragma unroll
      for (int et = 0; et < 4; ++et) {
        const int edge = et * 16 + col;
        short4 q = *(const short4*)(sY + SWM(edge, ch) + sub);
        f32x4 a = acc[tt][et];
        float v0 = lrelu(a[0] + bb.x + bf2f((unsigned short)q.x));
        float v1 = lrelu(a[1] + bb.y + bf2f((unsigned short)q.y));
        float v2 = lrelu(a[2] + bb.z + bf2f((unsigned short)q.z));
        float v3 = lrelu(a[3] + bb.w + bf2f((unsigned short)q.w));
        *(int2*)(sZ + SWM(edge, ch) + sub) = make_int2((int)pk2(v0, v1), (int)pk2(v2, v3));
        acc[tt][et] = (f32x4){0.f, 0.f, 0.f, 0.f};
      }
    }
  }
  __syncthreads();
  // ---------- Phase 2: L2 ; PF: ef -> sX (free), fold y ----------
  int4 y0, y1, y2, y3;
  if (PF) {
    *(int4*)(sX + SWX(r4, c4 * 2)) = xa;
    *(int4*)(sX + SWX(r4, c4 * 2 + 1)) = xb;
    y0.x = addbf(a0.x, d0.x); y0.y = addbf(a0.y, d0.y);
    y0.z = addbf(a0.z, d0.z); y0.w = addbf(a0.w, d0.w);
    y1.x = addbf(a1.x, d1.x); y1.y = addbf(a1.y, d1.y);
    y1.z = addbf(a1.z, d1.z); y1.w = addbf(a1.w, d1.w);
    y2.x = addbf(a2.x, d2.x); y2.y = addbf(a2.y, d2.y);
    y2.z = addbf(a2.z, d2.z); y2.w = addbf(a2.w, d2.w);
    y3.x = addbf(a3.x, d3.x); y3.y = addbf(a3.y, d3.y);
    y3.z = addbf(a3.z, d3.z); y3.w = addbf(a3.w, d3.w);
  }
  {
    bf16x8 f2[2][4];
    #pragma unroll
    for (int tt = 0; tt < 2; ++tt)
      #pragma unroll
      for (int s = 0; s < 4; ++s)
        f2[tt][s] = *(const bf16x8*)(wt + 24576 + ((((w * 2 + tt) * 4 + s) << 9) + lane * 8));
    #pragma unroll
    for (int et = 0; et < 4; ++et) {
      const int row = et * 16 + col;
      #pragma unroll
      for (int s = 0; s < 4; ++s) {
        bf16x8 b = *(const bf16x8*)(sZ + SWM(row, lq + s * 4));
        acc[0][et] = __builtin_amdgcn_mfma_f32_16x16x32_bf16(f2[0][s], b, acc[0][et], 0, 0, 0);
        acc[1][et] = __builtin_amdgcn_mfma_f32_16x16x32_bf16(f2[1][s], b, acc[1][et], 0, 0, 0);
      }
    }
    #pragma unroll
    for (int tt = 0; tt < 2; ++tt) {
      const int f0 = (w * 2 + tt) * 16 + lq * 4;
      const int ch = f0 >> 3, sub = f0 & 7;
      float4 bb = *(const float4*)(b2 + f0);
      #pragma unroll
      for (int et = 0; et < 4; ++et) {
        const int edge = et * 16 + col;
        f32x4 a = acc[tt][et];
        float v0 = lrelu(a[0] + bb.x), v1 = lrelu(a[1] + bb.y);
        float v2 = lrelu(a[2] + bb.z), v3 = lrelu(a[3] + bb.w);
        *(int2*)(sY + SWM(edge, ch) + sub) = make_int2((int)pk2(v0, v1), (int)pk2(v2, v3));
        acc[tt][et] = (f32x4){0.f, 0.f, 0.f, 0.f};
      }
    }
  }
  __syncthreads();
  // ---------- Phase 3: L3 -> global + stats ; PF: y -> sZ (free) ----------
  if (PF) {
    *(int4*)(sZ + SWM(r4, c4 * 4 + 0)) = y0;
    *(int4*)(sZ + SWM(r4, c4 * 4 + 1)) = y1;
    *(int4*)(sZ + SWM(r4, c4 * 4 + 2)) = y2;
    *(int4*)(sZ + SWM(r4, c4 * 4 + 3)) = y3;
  }
  {
    bf16x8 f3[2][4];
    #pragma unroll
    for (int tt = 0; tt < 2; ++tt)
      #pragma unroll
      for (int s = 0; s < 4; ++s)
        f3[tt][s] = *(const bf16x8*)(wt + 40960 + ((((w * 2 + tt) * 4 + s) << 9) + lane * 8));
    #pragma unroll
    for (int et = 0; et < 4; ++et) {
      const int row = et * 16 + col;
      #pragma unroll
      for (int s = 0; s < 4; ++s) {
        bf16x8 b = *(const bf16x8*)(sY + SWM(row, lq + s * 4));
        acc[0][et] = __builtin_amdgcn_mfma_f32_16x16x32_bf16(f3[0][s], b, acc[0][et], 0, 0, 0);
        acc[1][et] = __builtin_amdgcn_mfma_f32_16x16x32_bf16(f3[1][s], b, acc[1][et], 0, 0, 0);
      }
    }
    const size_t ebase = (size_t)t * 64;
    #pragma unroll
    for (int tt = 0; tt < 2; ++tt) {
      const int f0 = (w * 2 + tt) * 16 + lq * 4;
      float4 bb = *(const float4*)(b3 + f0);
      #pragma unroll
      for (int et = 0; et < 4; ++et) {
        const int edge = et * 16 + col;
        f32x4 a = acc[tt][et];
        float v0 = lrelu(a[0] + bb.x), v1 = lrelu(a[1] + bb.y);
        float v2 = lrelu(a[2] + bb.z), v3 = lrelu(a[3] + bb.w);
        sE[tt * 4 + 0] += v0; sQv[tt * 4 + 0] += v0 * v0;
        sE[tt * 4 + 1] += v1; sQv[tt * 4 + 1] += v1 * v1;
        sE[tt * 4 + 2] += v2; sQv[tt * 4 + 2] += v2 * v2;
        sE[tt * 4 + 3] += v3; sQv[tt * 4 + 3] += v3 * v3;
        if (USEWS) {
          *(int2*)(hout + (ebase + edge) * 128 + f0) =
              make_int2((int)pk2(v0, v1), (int)pk2(v2, v3));
        } else {
          *(float4*)(fout + (ebase + edge) * 128 + f0) = make_float4(v0, v1, v2, v3);
        }
        acc[tt][et] = (f32x4){0.f, 0.f, 0.f, 0.f};
      }
    }
  }
  __syncthreads();
}

// ---- 2 tiles per block, software-pipelined; 256 thr / 4 waves ----
// LDS 40KB -> 4 blocks/CU. Tile-B gathers issued during A-L1, landed in LDS
// as buffers free (ef->sX in A-L2, y->sQ in A-L3). h3 stored direct to global.
template<bool USEWS>
__global__ __launch_bounds__(256, 4) void gnn5(
    const float* __restrict__ edgef, const int* __restrict__ srcI,
    const int* __restrict__ dstI, const short* __restrict__ ybuf,
    const float* __restrict__ b1, const float* __restrict__ b2,
    const float* __restrict__ b3, const short* __restrict__ wt,
    float* __restrict__ partials, short* __restrict__ hout,
    float* __restrict__ fout) {
  __shared__ short sX[64 * 64];    // ef tile (swizzled)
  __shared__ short sP[64 * 128];   // A: y -> h2 ; B: h1
  __shared__ short sQ[64 * 128];   // A: h1      ; B: y -> h2

  const int tid = threadIdx.x;
  const int lane = tid & 63;
  const int w = tid >> 6;
  const int col = lane & 15;
  const int lq = lane >> 4;
  const int tA = blockIdx.x * 2, tB = tA + 1;
  const int r4 = tid >> 2, c4 = tid & 3;

  // prologue: stage tile A (ef->sX, folded y->sP)
  {
    int e = tA * 64 + r4;
    int si = srcI[e], di = dstI[e];
    const float4* efp = (const float4*)(edgef + (size_t)e * 64) + c4 * 4;
    float4 e0 = efp[0], e1 = efp[1], e2 = efp[2], e3 = efp[3];
    const int4* yps = (const int4*)(ybuf + (size_t)si * 128) + c4 * 4;
    const int4* ypd = (const int4*)(ybuf + (size_t)di * 128) + c4 * 4;
    int4 a0 = yps[0], a1 = yps[1], a2 = yps[2], a3 = yps[3];
    int4 d0 = ypd[0], d1 = ypd[1], d2 = ypd[2], d3 = ypd[3];
    int4 x0, x1;
    x0.x = (int)pk2(e0.x, e0.y); x0.y = (int)pk2(e0.z, e0.w);
    x0.z = (int)pk2(e1.x, e1.y); x0.w = (int)pk2(e1.z, e1.w);
    x1.x = (int)pk2(e2.x, e2.y); x1.y = (int)pk2(e2.z, e2.w);
    x1.z = (int)pk2(e3.x, e3.y); x1.w = (int)pk2(e3.z, e3.w);
    *(int4*)(sX + SWX(r4, c4 * 2)) = x0;
    *(int4*)(sX + SWX(r4, c4 * 2 + 1)) = x1;
    int4 y0, y1, y2, y3;
    y0.x = addbf(a0.x, d0.x); y0.y = addbf(a0.y, d0.y);
    y0.z = addbf(a0.z, d0.z); y0.w = addbf(a0.w, d0.w);
    y1.x = addbf(a1.x, d1.x); y1.y = addbf(a1.y, d1.y);
    y1.z = addbf(a1.z, d1.z); y1.w = addbf(a1.w, d1.w);
    y2.x = addbf(a2.x, d2.x); y2.y = addbf(a2.y, d2.y);
    y2.z = addbf(a2.z, d2.z); y2.w = addbf(a2.w, d2.w);
    y3.x = addbf(a3.x, d3.x); y3.y = addbf(a3.y, d3.y);
    y3.z = addbf(a3.z, d3.z); y3.w = addbf(a3.w, d3.w);
    *(int4*)(sP + SWM(r4, c4 * 4 + 0)) = y0;
    *(int4*)(sP + SWM(r4, c4 * 4 + 1)) = y1;
    *(int4*)(sP + SWM(r4, c4 * 4 + 2)) = y2;
    *(int4*)(sP + SWM(r4, c4 * 4 + 3)) = y3;
  }

  f32x4 acc[2][4];
  #pragma unroll
  for (int tt = 0; tt < 2; ++tt)
    #pragma unroll
    for (int et = 0; et < 4; ++et) acc[tt][et] = (f32x4){0.f, 0.f, 0.f, 0.f};
  float sE[8], sQv[8];
  #pragma unroll
  for (int i = 0; i < 8; ++i) { sE[i] = 0.f; sQv[i] = 0.f; }

  __syncthreads();

  doTile<USEWS, true>(tA, tB, edgef, srcI, dstI, ybuf, b1, b2, b3, wt,
                      hout, fout, sX, sP, sQ, acc, sE, sQv,
                      lane, w, col, lq, r4, c4);
  doTile<USEWS, false>(tB, 0, edgef, srcI, dstI, ybuf, b1, b2, b3, wt,
                       hout, fout, sX, sQ, sP, acc, sE, sQv,
                       lane, w, col, lq, r4, c4);

  // stats flush: butterfly over the 16 edge-lanes, then atomics
  #pragma unroll
  for (int m = 1; m <= 8; m <<= 1) {
    #pragma unroll
    for (int i = 0; i < 8; ++i) {
      sE[i] += __shfl_xor(sE[i], m, 64);
      sQv[i] += __shfl_xor(sQv[i], m, 64);
    }
  }
  if (col == 0) {
    float* pp = partials + (blockIdx.x & 63) * 256;
    #pragma unroll
    for (int tt = 0; tt < 2; ++tt) {
      const int f0 = (w * 2 + tt) * 16 + lq * 4;
      #pragma unroll
      for (int i = 0; i < 4; ++i) {
        atomicAdd(&pp[f0 + i], sE[tt * 4 + i]);
        atomicAdd(&pp[128 + f0 + i], sQv[tt * 4 + i]);
      }
    }
  }
}

// ---- per-node precompute: y = nf * W1b  (bf16 out) ----
__global__ __launch_bounds__(256) void nodeK(const float* __restrict__ nodef,
                                             const short* __restrict__ wt,
                                             short* __restrict__ y) {
  __shared__ short sN[64 * 136];
  const int tid = threadIdx.x;
  const int lane = tid & 63;
  const int w = tid >> 6;
  const int n0 = blockIdx.x * 64;
  const int r = tid >> 2, p4 = tid & 3;
  {
    int v = n0 + r;
    int vc = v < N_V ? v : N_V - 1;
    const float4* np = (const float4*)(nodef + (size_t)vc * 128) + p4 * 8;
    #pragma unroll
    for (int j = 0; j < 8; ++j) {
      float4 a = np[j];
      *(int2*)(sN + r * 136 + p4 * 32 + j * 4) =
          make_int2((int)pk2(a.x, a.y), (int)pk2(a.z, a.w));
    }
  }
  __syncthreads();
  const short* wb = wt + 8192;
  bf16x8 fr[8];
  #pragma unroll
  for (int nt = 0; nt < 2; ++nt)
    #pragma unroll
    for (int s = 0; s < 4; ++s)
      fr[nt * 4 + s] = *(const bf16x8*)(wb + ((((w * 2 + nt) * 4 + s) << 9) + lane * 8));
  f32x4 acc[8];
  #pragma unroll
  for (int i = 0; i < 8; ++i) acc[i] = (f32x4){0.f, 0.f, 0.f, 0.f};
  const int col = lane & 15;
  const int kb = (lane >> 4) * 8;
  #pragma unroll
  for (int et = 0; et < 4; ++et) {
    const short* bp = sN + (et * 16 + col) * 136 + kb;
    #pragma unroll
    for (int s = 0; s < 4; ++s) {
      bf16x8 b = *(const bf16x8*)(bp + s * 32);
      acc[0 + et] = __builtin_amdgcn_mfma_f32_16x16x32_bf16(fr[s], b, acc[0 + et], 0, 0, 0);
      acc[4 + et] = __builtin_amdgcn_mfma_f32_16x16x32_bf16(fr[4 + s], b, acc[4 + et], 0, 0, 0);
    }
  }
  __syncthreads();   // sN input reads done
  {
    const int fb = (lane >> 4) * 4;
    #pragma unroll
    for (int nt = 0; nt < 2; ++nt) {
      const int f0 = w * 32 + nt * 16 + fb;
      #pragma unroll
      for (int et = 0; et < 4; ++et) {
        f32x4 a = acc[nt * 4 + et];
        *(int2*)(sN + (et * 16 + col) * 136 + f0) =
            make_int2((int)pk2(a[0], a[1]), (int)pk2(a[2], a[3]));
      }
    }
  }
  __syncthreads();
  if (n0 + r < N_V) {
    #pragma unroll
    for (int j = 0; j < 4; ++j) {
      int4 tv = *(const int4*)(sN + r * 136 + p4 * 32 + j * 8);
      *(int4*)(y + (size_t)(n0 + r) * 128 + p4 * 32 + j * 8) = tv;
    }
  }
}

// ---- weight pack + partials zero ----
__global__ __launch_bounds__(256) void prepK(const float* __restrict__ W1,
                                             const float* __restrict__ W2,
                                             const float* __restrict__ W3,
                                             short* __restrict__ wt,
                                             float* __restrict__ partials) {
  int b = blockIdx.x, t = threadIdx.x;
  if (b < 64) { partials[b * 256 + t] = 0.f; return; }
  int g = (b - 64) * 256 + t;
  for (int fi = g; fi < 57344; fi += 32 * 256) {
    float val;
    if (fi < 8192) {                       // W1a: 8 tiles x 2 ksteps (K=64)
      int c = fi >> 9, r = fi & 511;
      int l = r >> 3, j = r & 7;
      int tt = c >> 1, s = c & 1;
      int n = tt * 16 + (l & 15);
      int k = s * 32 + (l >> 4) * 8 + j;
      val = W1[k * 128 + n];
    } else if (fi < 24576) {               // W1b: 8 tiles x 4 ksteps (rows 64..191)
      int f2 = fi - 8192;
      int c = f2 >> 9, r = f2 & 511;
      int l = r >> 3, j = r & 7;
      int tt = c >> 2, s = c & 3;
      int n = tt * 16 + (l & 15);
      int k = s * 32 + (l >> 4) * 8 + j;
      val = W1[(64 + k) * 128 + n];
    } else if (fi < 40960) {               // W2
      int f2 = fi - 24576;
      int c = f2 >> 9, r = f2 & 511;
      int l = r >> 3, j = r & 7;
      int tt = c >> 2, s = c & 3;
      int n = tt * 16 + (l & 15);
      int k = s * 32 + (l >> 4) * 8 + j;
      val = W2[k * 128 + n];
    } else {                               // W3
      int f3 = fi - 40960;
      int c = f3 >> 9, r = f3 & 511;
      int l = r >> 3, j = r & 7;
      int tt = c >> 2, s = c & 3;
      int n = tt * 16 + (l & 15);
      int k = s * 32 + (l >> 4) * 8 + j;
      val = W3[k * 128 + n];
    }
    wt[fi] = (short)f2bf(val);
  }
}

__global__ __launch_bounds__(256) void statsK(const float* __restrict__ partials,
                                              const float* __restrict__ gamma,
                                              const float* __restrict__ beta,
                                              float* __restrict__ scsh) {
  __shared__ float tmp[256];
  int t = threadIdx.x;
  float a = 0.f;
  #pragma unroll 8
  for (int r = 0; r < 64; ++r) a += partials[r * 256 + t];
  tmp[t] = a;
  __syncthreads();
  if (t < 128) {
    float S = tmp[t], S2 = tmp[t + 128];
    float mean = S / (float)N_E;
    float var = S2 / (float)N_E - mean * mean;   // biased, matches reference
    float inv = rsqrtf(var + BN_EPS);
    float sc = gamma[t] * inv;
    scsh[t] = sc;
    scsh[t + 128] = beta[t] - mean * sc;
  }
}

template<bool USEWS>
__global__ __launch_bounds__(256) void applyK(const short* __restrict__ h,
                                              const float* __restrict__ scsh,
                                              float* out) {
  const int TOT4 = N_E * 128 / 4;
  int j0 = blockIdx.x * 256 + threadIdx.x;
  int c4 = j0 & 31;
  float4 sc = *(const float4*)(scsh + c4 * 4);
  float4 sh = *(const float4*)(scsh + 128 + c4 * 4);
  int stride = gridDim.x * 256;
  for (int j = j0; j < TOT4; j += stride) {
    float4 v;
    if (USEWS) {
      short4 s = *(const short4*)(h + (size_t)j * 4);
      v.x = bf2f((unsigned short)s.x) * sc.x + sh.x;
      v.y = bf2f((unsigned short)s.y) * sc.y + sh.y;
      v.z = bf2f((unsigned short)s.z) * sc.z + sh.z;
      v.w = bf2f((unsigned short)s.w) * sc.w + sh.w;
    } else {
      float4 hv = ((const float4*)out)[j];
      v.x = hv.x * sc.x + sh.x;
      v.y = hv.y * sc.y + sh.y;
      v.z = hv.z * sc.z + sh.z;
      v.w = hv.w * sc.w + sh.w;
    }
    ((float4*)out)[j] = v;
  }
}

extern "C" void kernel_launch(void* const* d_in, const int* in_sizes, int n_in,
                              void* d_out, int out_size, void* d_ws, size_t ws_size,
                              hipStream_t stream) {
  const float* nodef = (const float*)d_in[0];
  const float* edgef = (const float*)d_in[1];
  const int* srcI = (const int*)d_in[2];
  const int* dstI = (const int*)d_in[3];
  const float* W1 = (const float*)d_in[4];
  const float* b1 = (const float*)d_in[5];
  const float* W2 = (const float*)d_in[6];
  const float* b2 = (const float*)d_in[7];
  const float* W3 = (const float*)d_in[8];
  const float* b3 = (const float*)d_in[9];
  const float* gamma = (const float*)d_in[10];
  const float* beta = (const float*)d_in[11];
  float* out = (float*)d_out;
  char* ws = (char*)d_ws;

  float* partials = (float*)(ws + PART_OFF);
  float* scsh = (float*)(ws + SCALE_OFF);
  short* wt = (short*)(ws + WT_OFF);
  short* ybuf;
  short* h = nullptr;
  bool usews;
  if (ws_size >= (size_t)META_END + Y_BYTES + H_BYTES) {
    ybuf = (short*)(ws + META_END);
    h = (short*)(ws + META_END + Y_BYTES);
    usews = true;
  } else if (ws_size >= (size_t)META_END + H_BYTES) {
    h = (short*)(ws + META_END);
    ybuf = (short*)((char*)d_out + OUT_BYTES - Y_BYTES);  // tail of out; rewritten by applyK last
    usews = true;
  } else {
    ybuf = (short*)(ws + META_END);
    usews = false;
  }

  prepK<<<96, 256, 0, stream>>>(W1, W2, W3, wt, partials);
  nodeK<<<782, 256, 0, stream>>>(nodef, wt, ybuf);
  if (usews) {
    gnn5<true><<<NT / 2, 256, 0, stream>>>(edgef, srcI, dstI, ybuf, b1, b2, b3,
                                           wt, partials, h, out);
  } else {
    gnn5<false><<<NT / 2, 256, 0, stream>>>(edgef, srcI, dstI, ybuf, b1, b2, b3,
                                            wt, partials, h, out);
  }
  statsK<<<1, 256, 0, stream>>>(partials, gamma, beta, scsh);
  if (usews) {
    applyK<true><<<2048, 256, 0, stream>>>(h, scsh, out);
  } else {
    applyK<false><<<2048, 256, 0, stream>>>(h, scsh, out);
  }
}